// Round 13
// baseline (311.881 us; speedup 1.0000x reference)
//
#include <hip/hip_runtime.h>
#include <math.h>

#define NB 64          // graphs
#define N0 1024        // nodes per graph (stage 1)
#define NEDGE 1048576  // total edges
#define EPG 16384      // edges per graph — input edges are graph-grouped
#define FIN 10
#define NCLS 10
#define KP1 205
#define KP2 41
#define KP3 9

static inline int ceil_div(int a, int b) { return (a + b - 1) / b; }

// ================= STAGE-1 MEGA: CSR + agg(x) + y@W1 + score + topk + pool =======
// One block per graph (1024 threads). All per-graph state in LDS/registers.
__global__ __launch_bounds__(1024) void stage1_mega_k(
    const float* __restrict__ x, const int* __restrict__ ei,
    const float* __restrict__ W1, const float* __restrict__ b1,
    const float* __restrict__ Ws1, const float* __restrict__ bs1,
    float* __restrict__ hout, float* __restrict__ hA, float* __restrict__ z,
    int* __restrict__ newid1, int2* __restrict__ csr2) {
    __shared__ float xl[N0 * 11];
    __shared__ float yl[N0 * 11];
    __shared__ float Wl[FIN * 128];
    __shared__ float Sc[128];
    __shared__ int   cnt[N0];      // degree -> cursor
    __shared__ float disl[N0];
    __shared__ int   scan[1024];
    __shared__ float v[1024];
    __shared__ int   ix[1024];
    __shared__ float zm[1024];
    __shared__ float zs[1024];
    __shared__ float hsl[N0];
    __shared__ float hsdl[N0];

    int b = blockIdx.x, t = threadIdx.x;
    const int ebase = b * EPG, nbase = b * N0;

    for (int u = t; u < FIN * 128; u += 1024) Wl[u] = W1[u];
    if (t < 128) Sc[t] = Ws1[t];
    const float* xg = x + (size_t)nbase * FIN;
    for (int u = t; u < N0 * FIN; u += 1024) {
        int r = u / FIN, c = u - r * FIN;
        xl[r * 11 + c] = xg[u];
    }
    cnt[t] = 0;
    __syncthreads();

    // ---- count (prefetch edge endpoints to registers) ----
    int sloc[EPG / 1024], dloc[EPG / 1024];
    #pragma unroll
    for (int u = 0; u < EPG / 1024; ++u) {
        int j = ebase + u * 1024 + t;
        sloc[u] = ei[j] - nbase;
        dloc[u] = ei[NEDGE + j] - nbase;
        atomicAdd(&cnt[dloc[u]], 1);
    }
    __syncthreads();
    int deg = cnt[t];
    scan[t] = deg;
    __syncthreads();
    #pragma unroll
    for (int s = 1; s < 1024; s <<= 1) {
        int tv = (t >= s) ? scan[t - s] : 0;
        __syncthreads();
        scan[t] += tv;
        __syncthreads();
    }
    int strt = scan[t] - deg;
    float di = rsqrtf((float)deg + 1.0f);
    disl[t] = di;
    __syncthreads();
    cnt[t] = strt;   // becomes cursor
    __syncthreads();

    // ---- scatter: csr2 entries {src_local, dis[src]} ----
    #pragma unroll
    for (int u = 0; u < EPG / 1024; ++u) {
        int pos = atomicAdd(&cnt[dloc[u]], 1);
        int2 o; o.x = sloc[u]; o.y = __float_as_int(disl[sloc[u]]);
        csr2[ebase + pos] = o;
    }
    __syncthreads();

    // ---- aggregate raw x (10-dim): yl = di*sum + di^2*x_self ----
    {
        float acc[FIN];
        #pragma unroll
        for (int f = 0; f < FIN; ++f) acc[f] = 0.f;
        const int2* cp = csr2 + ebase + strt;
        int j = 0;
        for (; j + 2 <= deg; j += 2) {
            int2 e0 = cp[j], e1 = cp[j + 1];
            int sl0 = e0.x * 11, sl1 = e1.x * 11;
            float w0 = __int_as_float(e0.y), w1 = __int_as_float(e1.y);
            #pragma unroll
            for (int f = 0; f < FIN; ++f) acc[f] += xl[sl0 + f] * w0 + xl[sl1 + f] * w1;
        }
        if (j < deg) {
            int2 e0 = cp[j];
            int sl0 = e0.x * 11;
            float w0 = __int_as_float(e0.y);
            #pragma unroll
            for (int f = 0; f < FIN; ++f) acc[f] += xl[sl0 + f] * w0;
        }
        float d2 = di * di;
        #pragma unroll
        for (int f = 0; f < FIN; ++f)
            yl[t * 11 + f] = di * acc[f] + d2 * xl[t * 11 + f];
    }
    __syncthreads();

    // ---- GEMM: hout = relu(yl @ W1 + b1), 8 nodes x 128 feats per iter ----
    {
        int f = t & 127, ng = t >> 7;
        float bf = b1[f];
        float* hp = hout + (size_t)nbase * 128;
        #pragma unroll 4
        for (int g = 0; g < 128; ++g) {
            int n = g * 8 + ng;
            float o = bf;
            #pragma unroll
            for (int k = 0; k < FIN; ++k) o += yl[n * 11 + k] * Wl[k * 128 + f];
            hp[g * 1024 + t] = fmaxf(o, 0.f);   // == (nbase+n)*128+f
        }
    }
    __syncthreads();

    // ---- hs/hsd per node: wave-per-node reduce from L2-hot hout ----
    {
        int w = t >> 6, lane = t & 63;
        const float2* hp = (const float2*)(hout + (size_t)nbase * 128);
        for (int it = 0; it < 64; ++it) {
            int n = it * 16 + w;
            float2 h2 = hp[n * 64 + lane];
            float part = h2.x * Sc[lane * 2] + h2.y * Sc[lane * 2 + 1];
            #pragma unroll
            for (int sh = 32; sh >= 1; sh >>= 1) part += __shfl_xor(part, sh);
            if (lane == 0) { hsl[n] = part; hsdl[n] = part * disl[n]; }
        }
    }
    __syncthreads();

    // ---- score ----
    {
        const int2* cp = csr2 + ebase + strt;
        float acc = 0.f;
        int j = 0;
        for (; j + 4 <= deg; j += 4) {
            int a0 = cp[j].x, a1 = cp[j+1].x, a2 = cp[j+2].x, a3 = cp[j+3].x;
            acc += hsdl[a0] + hsdl[a1] + hsdl[a2] + hsdl[a3];
        }
        for (; j < deg; ++j) acc += hsdl[cp[j].x];
        v[t] = di * acc + hsl[t] * (di * di) + bs1[0];
        ix[t] = t;
    }
    __syncthreads();

    // ---- bitonic sort (value desc, idx asc) ----
    for (int size = 2; size <= 1024; size <<= 1) {
        for (int stride = size >> 1; stride > 0; stride >>= 1) {
            if (t < 512) {
                int pos = 2 * t - (t & (stride - 1));
                int j2 = pos + stride;
                bool asc = (pos & size) == 0;
                float v0 = v[pos], v1 = v[j2];
                int i0 = ix[pos], i1 = ix[j2];
                bool jb = (v1 > v0) || (v1 == v0 && i1 < i0);
                bool sw = asc ? jb : !jb;
                if (sw) { v[pos] = v1; v[j2] = v0; ix[pos] = i1; ix[j2] = i0; }
            }
            __syncthreads();
        }
    }

    // ---- newid + gate ----
    if (t < KP1) newid1[nbase + ix[t]] = b * KP1 + t;
    else         newid1[nbase + ix[t]] = -1;
    if (t < KP1) zm[t] = tanhf(v[t]);
    __syncthreads();

    // ---- pool gather + readout (G=8 groups of 128 feats) ----
    {
        int g = t >> 7, f = t & 127;
        float vmax = -INFINITY, vsum = 0.f;
        for (int j = g; j < KP1; j += 8) {
            int src = nbase + ix[j];
            float val = hout[(size_t)src * 128 + f] * zm[j];
            hA[((size_t)b * KP1 + j) * 128 + f] = val;
            vmax = fmaxf(vmax, val); vsum += val;
        }
        __syncthreads();
        zm[t] = vmax; zs[t] = vsum;
        __syncthreads();
        if (t < 128) {
            float m = zm[t], s2 = zs[t];
            #pragma unroll
            for (int g2 = 1; g2 < 8; ++g2) { m = fmaxf(m, zm[g2 * 128 + t]); s2 += zs[g2 * 128 + t]; }
            z[b * 256 + t] = m;                       // first stage: plain write (no memset)
            z[b * 256 + 128 + t] = s2 / (float)KP1;
        }
    }
}

// ======== stage-2/3 CSR build: remap ORIGINAL edges via LDS newid slices ==========
template <int CUR, int PREVK, bool COMPOSE>
__global__ __launch_bounds__(1024) void build_csrN_k(const int* __restrict__ ei,
                                                     const int* __restrict__ nid1,
                                                     const int* __restrict__ nid2,
                                                     float* __restrict__ disg,
                                                     int* __restrict__ offg,
                                                     int* __restrict__ cntg,
                                                     int2* __restrict__ csr2) {
    __shared__ int n1[N0];
    __shared__ int n2c[COMPOSE ? PREVK : 1];
    __shared__ int cnt[CUR];
    __shared__ int cur[CUR];
    __shared__ float disl[CUR];
    __shared__ int scan[1024];
    int b = blockIdx.x, t = threadIdx.x;
    n1[t] = nid1[b * N0 + t];
    if (COMPOSE && t < PREVK) n2c[t] = nid2[b * PREVK + t];
    if (t < CUR) cnt[t] = 0;
    __syncthreads();
    const int ebase = b * EPG;
    const int nbase = b * N0;
    auto mapn = [&](int l) -> int {
        int g1 = n1[l];
        if (g1 < 0) return -1;
        if (!COMPOSE) return g1 - b * CUR;
        int g2 = n2c[g1 - b * PREVK];
        return (g2 < 0) ? -1 : (g2 - b * CUR);
    };
    #pragma unroll
    for (int u = 0; u < EPG / 1024; ++u) {
        int j = ebase + u * 1024 + t;
        int s = ei[j] - nbase, d = ei[NEDGE + j] - nbase;
        int ld = mapn(d);
        if (ld < 0) continue;
        if (mapn(s) < 0) continue;
        atomicAdd(&cnt[ld], 1);
    }
    __syncthreads();
    int v = (t < CUR) ? cnt[t] : 0;
    scan[t] = v;
    __syncthreads();
    #pragma unroll
    for (int s = 1; s < 1024; s <<= 1) {
        int tv = (t >= s) ? scan[t - s] : 0;
        __syncthreads();
        scan[t] += tv;
        __syncthreads();
    }
    if (t < CUR) {
        int excl = scan[t] - v;
        cur[t] = excl;
        float di = rsqrtf((float)v + 1.0f);
        disl[t] = di;
        offg[b * CUR + t] = ebase + excl;
        cntg[b * CUR + t] = v;
        disg[b * CUR + t] = di;
    }
    __syncthreads();
    #pragma unroll
    for (int u = 0; u < EPG / 1024; ++u) {
        int j = ebase + u * 1024 + t;
        int s = ei[j] - nbase, d = ei[NEDGE + j] - nbase;
        int ld = mapn(d);
        if (ld < 0) continue;
        int ls = mapn(s);
        if (ls < 0) continue;
        int pos = atomicAdd(&cur[ld], 1);
        int2 o; o.x = b * CUR + ls; o.y = __float_as_int(disl[ls]);
        csr2[ebase + pos] = o;
    }
}

// ---------------- GEMM (K=128): 64x64 tile, 4x4 per thread, register-tiled -----
__global__ __launch_bounds__(256) void gemm128_tiled_k(const float* __restrict__ A,
                                                       const float* __restrict__ W,
                                                       float* __restrict__ C, int n) {
    __shared__ float As[64][33];
    __shared__ float Wt[32][64];
    int tx = threadIdx.x & 15, ty = threadIdx.x >> 4;
    int r0 = blockIdx.x * 64;
    int c0 = blockIdx.y * 64;
    float4 acc0 = {0,0,0,0}, acc1 = {0,0,0,0}, acc2 = {0,0,0,0}, acc3 = {0,0,0,0};
    int u = threadIdx.x;
    for (int k0 = 0; k0 < 128; k0 += 32) {
        __syncthreads();
        {
            int rr = u >> 3, cc = (u & 7) * 4;
            #pragma unroll
            for (int h = 0; h < 2; ++h) {
                int r = rr + h * 32;
                float4 v = {0,0,0,0};
                if (r0 + r < n) v = *(const float4*)&A[(size_t)(r0 + r) * 128 + k0 + cc];
                As[r][cc] = v.x; As[r][cc+1] = v.y; As[r][cc+2] = v.z; As[r][cc+3] = v.w;
            }
        }
        {
            int kk = u >> 4, c = (u & 15) * 4;
            #pragma unroll
            for (int h = 0; h < 2; ++h) {
                float4 v = *(const float4*)&W[(size_t)(k0 + kk + h * 16) * 128 + c0 + c];
                *(float4*)&Wt[kk + h * 16][c] = v;
            }
        }
        __syncthreads();
        #pragma unroll
        for (int kk = 0; kk < 32; ++kk) {
            float4 wv = *(const float4*)&Wt[kk][tx * 4];
            float a0 = As[ty * 4 + 0][kk];
            float a1 = As[ty * 4 + 1][kk];
            float a2 = As[ty * 4 + 2][kk];
            float a3 = As[ty * 4 + 3][kk];
            acc0.x += a0 * wv.x; acc0.y += a0 * wv.y; acc0.z += a0 * wv.z; acc0.w += a0 * wv.w;
            acc1.x += a1 * wv.x; acc1.y += a1 * wv.y; acc1.z += a1 * wv.z; acc1.w += a1 * wv.w;
            acc2.x += a2 * wv.x; acc2.y += a2 * wv.y; acc2.z += a2 * wv.z; acc2.w += a2 * wv.w;
            acc3.x += a3 * wv.x; acc3.y += a3 * wv.y; acc3.z += a3 * wv.z; acc3.w += a3 * wv.w;
        }
    }
    int r = r0 + ty * 4;
    if (r + 0 < n) *(float4*)&C[(size_t)(r + 0) * 128 + c0 + tx * 4] = acc0;
    if (r + 1 < n) *(float4*)&C[(size_t)(r + 1) * 128 + c0 + tx * 4] = acc1;
    if (r + 2 < n) *(float4*)&C[(size_t)(r + 2) * 128 + c0 + tx * 4] = acc2;
    if (r + 3 < n) *(float4*)&C[(size_t)(r + 3) * 128 + c0 + tx * 4] = acc3;
}

// ---------- fused GCN aggregation (stages 2/3): wave-per-node, csr2, XCD-swizzled --
__global__ void gcn_agg_fused2_k(const float* __restrict__ hW, const int2* __restrict__ csr2,
                                 const int* __restrict__ off, const int* __restrict__ cnt,
                                 const float* __restrict__ dis, const float* __restrict__ bias,
                                 const float* __restrict__ Wsc,
                                 float* __restrict__ hout, float* __restrict__ hs,
                                 float* __restrict__ hsd, int n, int cpx) {
    int wg = ((blockIdx.x & 7) * cpx) + (blockIdx.x >> 3);
    int t = wg * blockDim.x + threadIdx.x;
    int i = t >> 6;              // one wave per node
    int lane = threadIdx.x & 63;
    if (i >= n) return;
    const float2* hW2 = (const float2*)hW;
    int s0 = off[i], e0 = s0 + cnt[i];
    float accx = 0.f, accy = 0.f;
    for (int j0 = s0; j0 < e0; j0 += 64) {
        int rem = e0 - j0;
        int m = rem < 64 ? rem : 64;
        int sv = 0; float wv = 0.f;
        if (lane < m) { int2 ec = csr2[j0 + lane]; sv = ec.x; wv = __int_as_float(ec.y); }
        int u = 0;
        for (; u + 4 <= m; u += 4) {
            int a0 = __shfl(sv, u + 0), a1 = __shfl(sv, u + 1);
            int a2 = __shfl(sv, u + 2), a3 = __shfl(sv, u + 3);
            float w0 = __shfl(wv, u + 0), w1 = __shfl(wv, u + 1);
            float w2 = __shfl(wv, u + 2), w3 = __shfl(wv, u + 3);
            float2 v0 = hW2[(size_t)a0 * 64 + lane];
            float2 v1 = hW2[(size_t)a1 * 64 + lane];
            float2 v2 = hW2[(size_t)a2 * 64 + lane];
            float2 v3 = hW2[(size_t)a3 * 64 + lane];
            accx += v0.x * w0 + v1.x * w1 + v2.x * w2 + v3.x * w3;
            accy += v0.y * w0 + v1.y * w1 + v2.y * w2 + v3.y * w3;
        }
        for (; u < m; ++u) {
            int s = __shfl(sv, u);
            float w = __shfl(wv, u);
            float2 v = hW2[(size_t)s * 64 + lane];
            accx += v.x * w; accy += v.y * w;
        }
    }
    float di = dis[i];
    float2 hv = hW2[(size_t)i * 64 + lane];
    float ox = fmaxf(di * accx + hv.x * (di * di) + bias[lane * 2], 0.f);
    float oy = fmaxf(di * accy + hv.y * (di * di) + bias[lane * 2 + 1], 0.f);
    float2 o; o.x = ox; o.y = oy;
    ((float2*)hout)[(size_t)i * 64 + lane] = o;
    float part = ox * Wsc[lane * 2] + oy * Wsc[lane * 2 + 1];
    #pragma unroll
    for (int sh = 32; sh >= 1; sh >>= 1) part += __shfl_xor(part, sh);
    if (lane == 0) { hs[i] = part; hsd[i] = part * di; }
}

// ---- fused: score gather (hsd via LDS) + top-k + newid + pool(tanh) + readout ----
template <int CAP, int K>
__global__ void score_topk_pool_k(const float* __restrict__ hout,
                                  const float* __restrict__ hs, const float* __restrict__ hsd,
                                  const int2* __restrict__ csr2, const int* __restrict__ off,
                                  const int* __restrict__ cnt, const float* __restrict__ dis,
                                  const float* __restrict__ bs,
                                  float* __restrict__ hA, float* __restrict__ z,
                                  int* __restrict__ newid, int cur) {
    __shared__ float v[CAP];
    __shared__ int ix[CAP];
    __shared__ float zm[CAP];
    __shared__ float zs[CAP];
    __shared__ float hl[CAP];
    int b = blockIdx.x, t = threadIdx.x;
    if (t < cur) hl[t] = hsd[b * cur + t];
    __syncthreads();
    float sc = -INFINITY;
    if (t < cur) {
        int i = b * cur + t;
        int s0 = off[i], e0 = s0 + cnt[i];
        float acc = 0.f;
        int j = s0;
        for (; j + 4 <= e0; j += 4) {
            int x0 = csr2[j].x, x1 = csr2[j+1].x, x2 = csr2[j+2].x, x3 = csr2[j+3].x;
            acc += hl[x0 - b*cur] + hl[x1 - b*cur] + hl[x2 - b*cur] + hl[x3 - b*cur];
        }
        for (; j < e0; ++j) acc += hl[csr2[j].x - b*cur];
        float di = dis[i];
        sc = di * acc + hs[i] * (di * di) + bs[0];
    }
    v[t] = sc; ix[t] = t;
    __syncthreads();
    for (int size = 2; size <= CAP; size <<= 1) {
        for (int stride = size >> 1; stride > 0; stride >>= 1) {
            if (t < CAP / 2) {
                int pos = 2 * t - (t & (stride - 1));
                int j2 = pos + stride;
                bool asc = (pos & size) == 0;
                float v0 = v[pos], v1 = v[j2];
                int i0 = ix[pos], i1 = ix[j2];
                bool jb = (v1 > v0) || (v1 == v0 && i1 < i0);
                bool sw = asc ? jb : !jb;
                if (sw) { v[pos] = v1; v[j2] = v0; ix[pos] = i1; ix[j2] = i0; }
            }
            __syncthreads();
        }
    }
    if (t < K)            newid[b * cur + ix[t]] = b * K + t;
    else if (ix[t] < cur) newid[b * cur + ix[t]] = -1;
    if (t < K) zm[t] = tanhf(v[t]);
    __syncthreads();
    if constexpr (CAP >= 128) {
        const int G = CAP / 128;
        int g = t >> 7, f = t & 127;
        float vmax = -INFINITY, vsum = 0.f;
        for (int j = g; j < K; j += G) {
            int src = b * cur + ix[j];
            float val = hout[(size_t)src * 128 + f] * zm[j];
            hA[((size_t)b * K + j) * 128 + f] = val;
            vmax = fmaxf(vmax, val); vsum += val;
        }
        __syncthreads();
        zm[t] = vmax; zs[t] = vsum;
        __syncthreads();
        if (t < 128) {
            float m = zm[t], s2 = zs[t];
            for (int g2 = 1; g2 < G; ++g2) { m = fmaxf(m, zm[g2 * 128 + t]); s2 += zs[g2 * 128 + t]; }
            z[b * 256 + t] += m;
            z[b * 256 + 128 + t] += s2 / (float)K;
        }
    } else {
        float vmax0 = -INFINITY, vsum0 = 0.f, vmax1 = -INFINITY, vsum1 = 0.f;
        for (int j = 0; j < K; ++j) {
            int src = b * cur + ix[j];
            float gt = zm[j];
            float a = hout[(size_t)src * 128 + t] * gt;
            float c = hout[(size_t)src * 128 + 64 + t] * gt;
            hA[((size_t)b * K + j) * 128 + t] = a;
            hA[((size_t)b * K + j) * 128 + 64 + t] = c;
            vmax0 = fmaxf(vmax0, a); vsum0 += a;
            vmax1 = fmaxf(vmax1, c); vsum1 += c;
        }
        z[b * 256 + t] += vmax0;
        z[b * 256 + 64 + t] += vmax1;
        z[b * 256 + 128 + t] += vsum0 / (float)K;
        z[b * 256 + 192 + t] += vsum1 / (float)K;
    }
}

// ---------------- MLP head + log_softmax ----------------
__global__ void mlp_head_k(const float* __restrict__ z,
                           const float* __restrict__ Wl1, const float* __restrict__ bl1,
                           const float* __restrict__ Wl2, const float* __restrict__ bl2,
                           const float* __restrict__ Wl3, const float* __restrict__ bl3,
                           float* __restrict__ out) {
    __shared__ float zr[256], h1[128], h2[64], lg[NCLS], red[2];
    int b = blockIdx.x, t = threadIdx.x;  // 128 threads
    zr[t] = z[b * 256 + t];
    zr[t + 128] = z[b * 256 + 128 + t];
    __syncthreads();
    float acc = bl1[t];
    #pragma unroll 8
    for (int i = 0; i < 256; ++i) acc += zr[i] * Wl1[i * 128 + t];
    h1[t] = fmaxf(acc, 0.f);
    __syncthreads();
    if (t < 64) {
        float a2 = bl2[t];
        #pragma unroll 8
        for (int i = 0; i < 128; ++i) a2 += h1[i] * Wl2[i * 64 + t];
        h2[t] = fmaxf(a2, 0.f);
    }
    __syncthreads();
    if (t < NCLS) {
        float a3 = bl3[t];
        #pragma unroll 8
        for (int i = 0; i < 64; ++i) a3 += h2[i] * Wl3[i * NCLS + t];
        lg[t] = a3;
    }
    __syncthreads();
    if (t == 0) {
        float m = lg[0];
        for (int i = 1; i < NCLS; ++i) m = fmaxf(m, lg[i]);
        float s = 0.f;
        for (int i = 0; i < NCLS; ++i) s += expf(lg[i] - m);
        red[0] = m; red[1] = logf(s);
    }
    __syncthreads();
    if (t < NCLS) out[b * NCLS + t] = lg[t] - red[0] - red[1];
}

// ---------------- host ----------------
extern "C" void kernel_launch(void* const* d_in, const int* in_sizes, int n_in,
                              void* d_out, int out_size, void* d_ws, size_t ws_size,
                              hipStream_t stream) {
    const float* x   = (const float*)d_in[0];
    const int*   ei  = (const int*)d_in[1];
    const float* W1  = (const float*)d_in[2];  const float* b1  = (const float*)d_in[3];
    const float* W2  = (const float*)d_in[4];  const float* b2  = (const float*)d_in[5];
    const float* W3  = (const float*)d_in[6];  const float* b3  = (const float*)d_in[7];
    const float* Ws1 = (const float*)d_in[8];  const float* bs1 = (const float*)d_in[9];
    const float* Ws2 = (const float*)d_in[10]; const float* bs2 = (const float*)d_in[11];
    const float* Ws3 = (const float*)d_in[12]; const float* bs3 = (const float*)d_in[13];
    const float* Wl1 = (const float*)d_in[14]; const float* bl1 = (const float*)d_in[15];
    const float* Wl2 = (const float*)d_in[16]; const float* bl2 = (const float*)d_in[17];
    const float* Wl3 = (const float*)d_in[18]; const float* bl3 = (const float*)d_in[19];
    float* out = (float*)d_out;

    const int NMAX = NB * N0;  // 65536
    const int N1 = NB * KP1;   // 13120
    const int N2 = NB * KP2;   // 2624

    char* p = (char*)d_ws;
    float* z      = (float*)p; p += (size_t)NB * 256 * 4;
    float* hW     = (float*)p; p += (size_t)N1 * 128 * 4;   // stage2/3 gemm out
    float* hout   = (float*)p; p += (size_t)NMAX * 128 * 4;
    float* hA     = (float*)p; p += (size_t)N1 * 128 * 4;
    float* dis    = (float*)p; p += (size_t)NMAX * 4;
    float* hs     = (float*)p; p += (size_t)NMAX * 4;
    float* hsd    = (float*)p; p += (size_t)NMAX * 4;
    int* newid1   = (int*)p;   p += (size_t)NMAX * 4;
    int* newid2   = (int*)p;   p += (size_t)N1 * 4;
    int* off      = (int*)p;   p += (size_t)NMAX * 4;
    int* cnt      = (int*)p;   p += (size_t)NMAX * 4;
    int2* csr2    = (int2*)p;  p += (size_t)NEDGE * 8;

    // ---------------- stage 1 (one mega kernel) ----------------
    stage1_mega_k<<<NB, 1024, 0, stream>>>(x, ei, W1, b1, Ws1, bs1,
                                           hout, hA, z, newid1, csr2);

    // ---------------- stage 2 ----------------
    build_csrN_k<KP1, KP1, false><<<NB, 1024, 0, stream>>>(ei, newid1, nullptr, dis, off, cnt, csr2);
    {
        dim3 g(ceil_div(N1, 64), 2);
        gemm128_tiled_k<<<g, 256, 0, stream>>>(hA, W2, hW, N1);
    }
    gcn_agg_fused2_k<<<N1 / 4, 256, 0, stream>>>(
        hW, csr2, off, cnt, dis, b2, Ws2, hout, hs, hsd, N1, N1 / 32);
    score_topk_pool_k<256, KP2><<<NB, 256, 0, stream>>>(
        hout, hs, hsd, csr2, off, cnt, dis, bs2, hA, z, newid2, KP1);

    // ---------------- stage 3 ----------------
    build_csrN_k<KP2, KP1, true><<<NB, 1024, 0, stream>>>(ei, newid1, newid2, dis, off, cnt, csr2);
    {
        dim3 g(ceil_div(N2, 64), 2);
        gemm128_tiled_k<<<g, 256, 0, stream>>>(hA, W3, hW, N2);
    }
    gcn_agg_fused2_k<<<N2 / 4, 256, 0, stream>>>(
        hW, csr2, off, cnt, dis, b3, Ws3, hout, hs, hsd, N2, N2 / 32);
    score_topk_pool_k<64, KP3><<<NB, 64, 0, stream>>>(
        hout, hs, hsd, csr2, off, cnt, dis, bs3, hA, z, newid1, KP2);

    mlp_head_k<<<NB, 128, 0, stream>>>(z, Wl1, bl1, Wl2, bl2, Wl3, bl3, out);
}

// Round 14
// 271.678 us; speedup vs baseline: 1.1480x; 1.1480x over previous
//
#include <hip/hip_runtime.h>
#include <math.h>

#define NB 64          // graphs
#define N0 1024        // nodes per graph (stage 1)
#define NEDGE 1048576  // total edges
#define EPG 16384      // edges per graph — input edges are graph-grouped
#define FIN 10
#define NCLS 10
#define KP1 205
#define KP2 41
#define KP3 9

static inline int ceil_div(int a, int b) { return (a + b - 1) / b; }

// ======== stage-1 CSR build: one block per graph, all-LDS (no global atomics) =====
__global__ __launch_bounds__(1024) void build_csr1_k(const int* __restrict__ ei,
                                                     float* __restrict__ disg,
                                                     int* __restrict__ offg,
                                                     int* __restrict__ cntg,
                                                     int2* __restrict__ csr2) {
    __shared__ int cnt[N0];
    __shared__ int cur[N0];
    __shared__ float disl[N0];
    __shared__ int scan[1024];
    int b = blockIdx.x, t = threadIdx.x;
    cnt[t] = 0;
    __syncthreads();
    const int ebase = b * EPG;
    const int nbase = b * N0;
    #pragma unroll
    for (int u = 0; u < EPG / 1024; ++u) {
        int d = ei[NEDGE + ebase + u * 1024 + t] - nbase;
        atomicAdd(&cnt[d], 1);
    }
    __syncthreads();
    int v = cnt[t];
    scan[t] = v;
    __syncthreads();
    #pragma unroll
    for (int s = 1; s < 1024; s <<= 1) {
        int tv = (t >= s) ? scan[t - s] : 0;
        __syncthreads();
        scan[t] += tv;
        __syncthreads();
    }
    int excl = scan[t] - v;
    cur[t] = excl;
    float di = rsqrtf((float)v + 1.0f);
    disl[t] = di;
    offg[nbase + t] = ebase + excl;
    cntg[nbase + t] = v;
    disg[nbase + t] = di;
    __syncthreads();
    #pragma unroll
    for (int u = 0; u < EPG / 1024; ++u) {
        int j = ebase + u * 1024 + t;
        int s = ei[j], d = ei[NEDGE + j] - nbase;
        int pos = atomicAdd(&cur[d], 1);
        int2 o; o.x = s; o.y = __float_as_int(disl[s - nbase]);
        csr2[ebase + pos] = o;
    }
}

// ---------------- stage-1: aggregate RAW x (10-dim) pre-GEMM, LDS-staged graph ----
__global__ __launch_bounds__(256) void agg10_k(const float* __restrict__ x,
                                               const int2* __restrict__ csr2,
                                               const int* __restrict__ off,
                                               const int* __restrict__ cnt,
                                               const float* __restrict__ dis,
                                               float* __restrict__ y) {
    __shared__ float xl[N0 * 11];
    int b = blockIdx.x >> 2, chunk = blockIdx.x & 3;
    const float* xg = x + (size_t)b * (N0 * FIN);
    for (int u = threadIdx.x; u < N0 * FIN; u += 256) {
        int r = u / FIN, c = u - r * FIN;
        xl[r * 11 + c] = xg[u];
    }
    __syncthreads();
    int li = chunk * 256 + threadIdx.x;
    int i  = b * N0 + li;
    int s0 = off[i], m = cnt[i];
    int base = b * N0;
    float acc[FIN];
    #pragma unroll
    for (int f = 0; f < FIN; ++f) acc[f] = 0.f;
    int j = 0;
    for (; j + 2 <= m; j += 2) {
        int2 e0 = csr2[s0 + j], e1 = csr2[s0 + j + 1];
        int sl0 = (e0.x - base) * 11, sl1 = (e1.x - base) * 11;
        float w0 = __int_as_float(e0.y), w1 = __int_as_float(e1.y);
        #pragma unroll
        for (int f = 0; f < FIN; ++f) acc[f] += xl[sl0 + f] * w0 + xl[sl1 + f] * w1;
    }
    if (j < m) {
        int2 e0 = csr2[s0 + j];
        int sl0 = (e0.x - base) * 11;
        float w0 = __int_as_float(e0.y);
        #pragma unroll
        for (int f = 0; f < FIN; ++f) acc[f] += xl[sl0 + f] * w0;
    }
    float di = dis[i], d2 = di * di;
    #pragma unroll
    for (int f = 0; f < FIN; ++f)
        y[(size_t)i * FIN + f] = di * acc[f] + d2 * xl[li * 11 + f];
}

// ---------------- fused: hout = relu(y@W + b); hs = hout@Wsc; hsd = hs*dis -------
__global__ void gemm_fin_fused_k(const float* __restrict__ y, const float* __restrict__ W,
                                 const float* __restrict__ bb, const float* __restrict__ Wsc,
                                 const float* __restrict__ dis,
                                 float* __restrict__ hout, float* __restrict__ hs,
                                 float* __restrict__ hsd, int n) {
    __shared__ float Ws[FIN * 128];
    __shared__ float Sc[128];
    for (int u = threadIdx.x; u < FIN * 128; u += 256) Ws[u] = W[u];
    if (threadIdx.x < 128) Sc[threadIdx.x] = Wsc[threadIdx.x];
    __syncthreads();
    int t = blockIdx.x * 256 + threadIdx.x;
    int i = t >> 6, lane = threadIdx.x & 63;
    if (i >= n) return;
    float a = (lane < FIN) ? y[(size_t)i * FIN + lane] : 0.f;
    const float2* W2 = (const float2*)Ws;
    float ax = bb[lane * 2], ay = bb[lane * 2 + 1];
    #pragma unroll
    for (int k = 0; k < FIN; ++k) {
        float ak = __shfl(a, k);
        float2 w = W2[k * 64 + lane];
        ax += ak * w.x; ay += ak * w.y;
    }
    ax = fmaxf(ax, 0.f); ay = fmaxf(ay, 0.f);
    float2 o; o.x = ax; o.y = ay;
    ((float2*)hout)[(size_t)i * 64 + lane] = o;
    float part = ax * Sc[lane * 2] + ay * Sc[lane * 2 + 1];
    #pragma unroll
    for (int sh = 32; sh >= 1; sh >>= 1) part += __shfl_xor(part, sh);
    if (lane == 0) { hs[i] = part; hsd[i] = part * dis[i]; }
}

// ====== STAGE-1 top-k + pool + readout + BUILD STAGE-2 CSR (one 64x1024 kernel) ===
__global__ __launch_bounds__(1024) void s1_topk_build2_k(
    const float* __restrict__ hout, const float* __restrict__ hs,
    const float* __restrict__ hsd, const int* __restrict__ ei,
    int2* __restrict__ csr,                       // in: stage-1 CSR, out: stage-2 CSR
    const int* __restrict__ off1, const int* __restrict__ cnt1,
    const float* __restrict__ dis1, const float* __restrict__ bs1,
    float* __restrict__ hA, float* __restrict__ z, int* __restrict__ newid1,
    int* __restrict__ off2, int* __restrict__ cnt2g, float* __restrict__ dis2g) {
    __shared__ float v[1024];
    __shared__ int   ix[1024];
    __shared__ float zm[1024];
    __shared__ float zs[1024];
    __shared__ float hl[1024];
    __shared__ int   n1l[1024];
    __shared__ int   c2[KP1];
    __shared__ int   cur2[KP1];
    __shared__ float d2l[KP1];
    __shared__ int   scan[1024];
    int b = blockIdx.x, t = threadIdx.x;
    const int nbase = b * N0, ebase = b * EPG;

    hl[t] = hsd[nbase + t];
    __syncthreads();
    // score
    {
        int s0 = off1[nbase + t], e0 = s0 + cnt1[nbase + t];
        float acc = 0.f;
        int j = s0;
        for (; j + 4 <= e0; j += 4) {
            int a0 = csr[j].x, a1 = csr[j+1].x, a2 = csr[j+2].x, a3 = csr[j+3].x;
            acc += hl[a0 - nbase] + hl[a1 - nbase] + hl[a2 - nbase] + hl[a3 - nbase];
        }
        for (; j < e0; ++j) acc += hl[csr[j].x - nbase];
        float di = dis1[nbase + t];
        v[t] = di * acc + hs[nbase + t] * (di * di) + bs1[0];
        ix[t] = t;
    }
    __syncthreads();
    // bitonic sort (desc, idx asc), CAP=1024
    for (int size = 2; size <= 1024; size <<= 1) {
        for (int stride = size >> 1; stride > 0; stride >>= 1) {
            if (t < 512) {
                int pos = 2 * t - (t & (stride - 1));
                int j2 = pos + stride;
                bool asc = (pos & size) == 0;
                float v0 = v[pos], v1 = v[j2];
                int i0 = ix[pos], i1 = ix[j2];
                bool jb = (v1 > v0) || (v1 == v0 && i1 < i0);
                bool sw = asc ? jb : !jb;
                if (sw) { v[pos] = v1; v[j2] = v0; ix[pos] = i1; ix[j2] = i0; }
            }
            __syncthreads();
        }
    }
    // newid (global + local rank map)
    {
        int node = ix[t];
        int loc = (t < KP1) ? t : -1;
        n1l[node] = loc;
        newid1[nbase + node] = (t < KP1) ? (b * KP1 + t) : -1;
        if (t < KP1) zm[t] = tanhf(v[t]);
    }
    __syncthreads();
    // pool gather + readout (G=8)
    {
        int g = t >> 7, f = t & 127;
        float vmax = -INFINITY, vsum = 0.f;
        for (int j = g; j < KP1; j += 8) {
            int src = nbase + ix[j];
            float val = hout[(size_t)src * 128 + f] * zm[j];
            hA[((size_t)b * KP1 + j) * 128 + f] = val;
            vmax = fmaxf(vmax, val); vsum += val;
        }
        __syncthreads();
        zm[t] = vmax; zs[t] = vsum;
        __syncthreads();
        if (t < 128) {
            float m = zm[t], s2 = zs[t];
            #pragma unroll
            for (int g2 = 1; g2 < 8; ++g2) { m = fmaxf(m, zm[g2 * 128 + t]); s2 += zs[g2 * 128 + t]; }
            z[b * 256 + t] = m;
            z[b * 256 + 128 + t] = s2 / (float)KP1;
        }
    }
    __syncthreads();
    // ---- build stage-2 CSR (overwrite this graph's csr window) ----
    if (t < KP1) c2[t] = 0;
    __syncthreads();
    int sl[EPG / 1024], dl[EPG / 1024];
    #pragma unroll
    for (int u = 0; u < EPG / 1024; ++u) {
        int j = ebase + u * 1024 + t;
        int s = ei[j] - nbase, d = ei[NEDGE + j] - nbase;
        int ls = n1l[s], ld = n1l[d];
        bool alive = (ls >= 0 && ld >= 0);
        sl[u] = alive ? ls : -1; dl[u] = ld;
        if (alive) atomicAdd(&c2[ld], 1);
    }
    __syncthreads();
    int vv = (t < KP1) ? c2[t] : 0;
    scan[t] = vv;
    __syncthreads();
    #pragma unroll
    for (int s = 1; s < 1024; s <<= 1) {
        int tv = (t >= s) ? scan[t - s] : 0;
        __syncthreads();
        scan[t] += tv;
        __syncthreads();
    }
    if (t < KP1) {
        int excl = scan[t] - vv;
        cur2[t] = excl;
        float dd = rsqrtf((float)vv + 1.0f);
        d2l[t] = dd;
        off2[b * KP1 + t] = ebase + excl;
        cnt2g[b * KP1 + t] = vv;
        dis2g[b * KP1 + t] = dd;
    }
    __syncthreads();
    #pragma unroll
    for (int u = 0; u < EPG / 1024; ++u) {
        if (sl[u] < 0) continue;
        int pos = atomicAdd(&cur2[dl[u]], 1);
        int2 o; o.x = b * KP1 + sl[u]; o.y = __float_as_int(d2l[sl[u]]);
        csr[ebase + pos] = o;
    }
}

// ---------------- GEMM (K=128): 64x64 tile, 4x4 per thread, register-tiled -----
__global__ __launch_bounds__(256) void gemm128_tiled_k(const float* __restrict__ A,
                                                       const float* __restrict__ W,
                                                       float* __restrict__ C, int n) {
    __shared__ float As[64][33];
    __shared__ float Wt[32][64];
    int tx = threadIdx.x & 15, ty = threadIdx.x >> 4;
    int r0 = blockIdx.x * 64;
    int c0 = blockIdx.y * 64;
    float4 acc0 = {0,0,0,0}, acc1 = {0,0,0,0}, acc2 = {0,0,0,0}, acc3 = {0,0,0,0};
    int u = threadIdx.x;
    for (int k0 = 0; k0 < 128; k0 += 32) {
        __syncthreads();
        {
            int rr = u >> 3, cc = (u & 7) * 4;
            #pragma unroll
            for (int h = 0; h < 2; ++h) {
                int r = rr + h * 32;
                float4 v = {0,0,0,0};
                if (r0 + r < n) v = *(const float4*)&A[(size_t)(r0 + r) * 128 + k0 + cc];
                As[r][cc] = v.x; As[r][cc+1] = v.y; As[r][cc+2] = v.z; As[r][cc+3] = v.w;
            }
        }
        {
            int kk = u >> 4, c = (u & 15) * 4;
            #pragma unroll
            for (int h = 0; h < 2; ++h) {
                float4 v = *(const float4*)&W[(size_t)(k0 + kk + h * 16) * 128 + c0 + c];
                *(float4*)&Wt[kk + h * 16][c] = v;
            }
        }
        __syncthreads();
        #pragma unroll
        for (int kk = 0; kk < 32; ++kk) {
            float4 wv = *(const float4*)&Wt[kk][tx * 4];
            float a0 = As[ty * 4 + 0][kk];
            float a1 = As[ty * 4 + 1][kk];
            float a2 = As[ty * 4 + 2][kk];
            float a3 = As[ty * 4 + 3][kk];
            acc0.x += a0 * wv.x; acc0.y += a0 * wv.y; acc0.z += a0 * wv.z; acc0.w += a0 * wv.w;
            acc1.x += a1 * wv.x; acc1.y += a1 * wv.y; acc1.z += a1 * wv.z; acc1.w += a1 * wv.w;
            acc2.x += a2 * wv.x; acc2.y += a2 * wv.y; acc2.z += a2 * wv.z; acc2.w += a2 * wv.w;
            acc3.x += a3 * wv.x; acc3.y += a3 * wv.y; acc3.z += a3 * wv.z; acc3.w += a3 * wv.w;
        }
    }
    int r = r0 + ty * 4;
    if (r + 0 < n) *(float4*)&C[(size_t)(r + 0) * 128 + c0 + tx * 4] = acc0;
    if (r + 1 < n) *(float4*)&C[(size_t)(r + 1) * 128 + c0 + tx * 4] = acc1;
    if (r + 2 < n) *(float4*)&C[(size_t)(r + 2) * 128 + c0 + tx * 4] = acc2;
    if (r + 3 < n) *(float4*)&C[(size_t)(r + 3) * 128 + c0 + tx * 4] = acc3;
}

// ---------- fused GCN aggregation (stages 2/3): wave-per-node, csr2, XCD-swizzled --
__global__ void gcn_agg_fused2_k(const float* __restrict__ hW, const int2* __restrict__ csr2,
                                 const int* __restrict__ off, const int* __restrict__ cnt,
                                 const float* __restrict__ dis, const float* __restrict__ bias,
                                 const float* __restrict__ Wsc,
                                 float* __restrict__ hout, float* __restrict__ hs,
                                 float* __restrict__ hsd, int n, int cpx) {
    int wg = ((blockIdx.x & 7) * cpx) + (blockIdx.x >> 3);
    int t = wg * blockDim.x + threadIdx.x;
    int i = t >> 6;              // one wave per node
    int lane = threadIdx.x & 63;
    if (i >= n) return;
    const float2* hW2 = (const float2*)hW;
    int s0 = off[i], e0 = s0 + cnt[i];
    float accx = 0.f, accy = 0.f;
    for (int j0 = s0; j0 < e0; j0 += 64) {
        int rem = e0 - j0;
        int m = rem < 64 ? rem : 64;
        int sv = 0; float wv = 0.f;
        if (lane < m) { int2 ec = csr2[j0 + lane]; sv = ec.x; wv = __int_as_float(ec.y); }
        int u = 0;
        for (; u + 4 <= m; u += 4) {
            int a0 = __shfl(sv, u + 0), a1 = __shfl(sv, u + 1);
            int a2 = __shfl(sv, u + 2), a3 = __shfl(sv, u + 3);
            float w0 = __shfl(wv, u + 0), w1 = __shfl(wv, u + 1);
            float w2 = __shfl(wv, u + 2), w3 = __shfl(wv, u + 3);
            float2 v0 = hW2[(size_t)a0 * 64 + lane];
            float2 v1 = hW2[(size_t)a1 * 64 + lane];
            float2 v2 = hW2[(size_t)a2 * 64 + lane];
            float2 v3 = hW2[(size_t)a3 * 64 + lane];
            accx += v0.x * w0 + v1.x * w1 + v2.x * w2 + v3.x * w3;
            accy += v0.y * w0 + v1.y * w1 + v2.y * w2 + v3.y * w3;
        }
        for (; u < m; ++u) {
            int s = __shfl(sv, u);
            float w = __shfl(wv, u);
            float2 v = hW2[(size_t)s * 64 + lane];
            accx += v.x * w; accy += v.y * w;
        }
    }
    float di = dis[i];
    float2 hv = hW2[(size_t)i * 64 + lane];
    float ox = fmaxf(di * accx + hv.x * (di * di) + bias[lane * 2], 0.f);
    float oy = fmaxf(di * accy + hv.y * (di * di) + bias[lane * 2 + 1], 0.f);
    float2 o; o.x = ox; o.y = oy;
    ((float2*)hout)[(size_t)i * 64 + lane] = o;
    float part = ox * Wsc[lane * 2] + oy * Wsc[lane * 2 + 1];
    #pragma unroll
    for (int sh = 32; sh >= 1; sh >>= 1) part += __shfl_xor(part, sh);
    if (lane == 0) { hs[i] = part; hsd[i] = part * di; }
}

// ====== STAGE-2 top-k + pool + readout + BUILD STAGE-3 CSR (64x1024) =============
__global__ __launch_bounds__(1024) void s2_topk_build3_k(
    const float* __restrict__ hout, const float* __restrict__ hs,
    const float* __restrict__ hsd, const int* __restrict__ ei,
    int2* __restrict__ csr,
    const int* __restrict__ off2, const int* __restrict__ cnt2,
    const float* __restrict__ dis2, const float* __restrict__ bs2,
    const int* __restrict__ newid1,
    float* __restrict__ hA, float* __restrict__ z,
    int* __restrict__ off3, int* __restrict__ cnt3g, float* __restrict__ dis3g) {
    __shared__ float v[256];
    __shared__ int   ix[256];
    __shared__ float hl[256];
    __shared__ float zm[1024];
    __shared__ float zs[1024];
    __shared__ int   n1g[1024];   // orig-local -> stage2-local or -1
    __shared__ int   n2l[KP1];    // stage2-local -> stage3-local or -1
    __shared__ int   c3[KP2];
    __shared__ int   cur3[KP2];
    __shared__ float d3l[KP2];
    __shared__ int   scan[1024];
    int b = blockIdx.x, t = threadIdx.x;
    const int nbase = b * N0, ebase = b * EPG;

    if (t < KP1) hl[t] = hsd[b * KP1 + t];
    { int g1 = newid1[nbase + t]; n1g[t] = (g1 >= 0) ? (g1 - b * KP1) : -1; }
    __syncthreads();
    // score
    float sc = -INFINITY;
    if (t < KP1) {
        int i = b * KP1 + t;
        int s0 = off2[i], e0 = s0 + cnt2[i];
        float acc = 0.f;
        int j = s0;
        for (; j + 4 <= e0; j += 4) {
            int a0 = csr[j].x, a1 = csr[j+1].x, a2 = csr[j+2].x, a3 = csr[j+3].x;
            acc += hl[a0 - b*KP1] + hl[a1 - b*KP1] + hl[a2 - b*KP1] + hl[a3 - b*KP1];
        }
        for (; j < e0; ++j) acc += hl[csr[j].x - b*KP1];
        float di = dis2[i];
        sc = di * acc + hs[i] * (di * di) + bs2[0];
    }
    if (t < 256) { v[t] = sc; ix[t] = t; }
    __syncthreads();
    // bitonic sort CAP=256
    for (int size = 2; size <= 256; size <<= 1) {
        for (int stride = size >> 1; stride > 0; stride >>= 1) {
            if (t < 128) {
                int pos = 2 * t - (t & (stride - 1));
                int j2 = pos + stride;
                bool asc = (pos & size) == 0;
                float v0 = v[pos], v1 = v[j2];
                int i0 = ix[pos], i1 = ix[j2];
                bool jb = (v1 > v0) || (v1 == v0 && i1 < i0);
                bool sw = asc ? jb : !jb;
                if (sw) { v[pos] = v1; v[j2] = v0; ix[pos] = i1; ix[j2] = i0; }
            }
            __syncthreads();
        }
    }
    if (t < 256) { int node = ix[t]; if (node < KP1) n2l[node] = (t < KP2) ? t : -1; }
    if (t < KP2) zm[t] = tanhf(v[t]);
    __syncthreads();
    // pool gather + readout (G=8)
    {
        int g = t >> 7, f = t & 127;
        float vmax = -INFINITY, vsum = 0.f;
        for (int j = g; j < KP2; j += 8) {
            int src = b * KP1 + ix[j];
            float val = hout[(size_t)src * 128 + f] * zm[j];
            hA[((size_t)b * KP2 + j) * 128 + f] = val;
            vmax = fmaxf(vmax, val); vsum += val;
        }
        __syncthreads();
        zm[t] = vmax; zs[t] = vsum;
        __syncthreads();
        if (t < 128) {
            float m = zm[t], s2 = zs[t];
            #pragma unroll
            for (int g2 = 1; g2 < 8; ++g2) { m = fmaxf(m, zm[g2 * 128 + t]); s2 += zs[g2 * 128 + t]; }
            z[b * 256 + t] += m;
            z[b * 256 + 128 + t] += s2 / (float)KP2;
        }
    }
    __syncthreads();
    // ---- build stage-3 CSR over ORIGINAL edges, composed map ----
    if (t < KP2) c3[t] = 0;
    __syncthreads();
    int sl[EPG / 1024], dl[EPG / 1024];
    #pragma unroll
    for (int u = 0; u < EPG / 1024; ++u) {
        int j = ebase + u * 1024 + t;
        int s = ei[j] - nbase, d = ei[NEDGE + j] - nbase;
        int a = n1g[s], bb = n1g[d];
        int ls = -1, ld = -1;
        if (a >= 0 && bb >= 0) { ls = n2l[a]; ld = n2l[bb]; }
        bool alive = (ls >= 0 && ld >= 0);
        sl[u] = alive ? ls : -1; dl[u] = ld;
        if (alive) atomicAdd(&c3[ld], 1);
    }
    __syncthreads();
    int vv = (t < KP2) ? c3[t] : 0;
    scan[t] = vv;
    __syncthreads();
    #pragma unroll
    for (int s = 1; s < 1024; s <<= 1) {
        int tv = (t >= s) ? scan[t - s] : 0;
        __syncthreads();
        scan[t] += tv;
        __syncthreads();
    }
    if (t < KP2) {
        int excl = scan[t] - vv;
        cur3[t] = excl;
        float dd = rsqrtf((float)vv + 1.0f);
        d3l[t] = dd;
        off3[b * KP2 + t] = ebase + excl;
        cnt3g[b * KP2 + t] = vv;
        dis3g[b * KP2 + t] = dd;
    }
    __syncthreads();
    #pragma unroll
    for (int u = 0; u < EPG / 1024; ++u) {
        if (sl[u] < 0) continue;
        int pos = atomicAdd(&cur3[dl[u]], 1);
        int2 o; o.x = b * KP2 + sl[u]; o.y = __float_as_int(d3l[sl[u]]);
        csr[ebase + pos] = o;
    }
}

// ====== STAGE-3 top-k + pool + readout + MLP head (64x128) =======================
__global__ __launch_bounds__(128) void s3_topk_mlp_k(
    const float* __restrict__ hout, const float* __restrict__ hs,
    const float* __restrict__ hsd, const int2* __restrict__ csr,
    const int* __restrict__ off3, const int* __restrict__ cnt3,
    const float* __restrict__ dis3, const float* __restrict__ bs3,
    const float* __restrict__ z,
    const float* __restrict__ Wl1, const float* __restrict__ bl1,
    const float* __restrict__ Wl2, const float* __restrict__ bl2,
    const float* __restrict__ Wl3, const float* __restrict__ bl3,
    float* __restrict__ out) {
    __shared__ float hl[KP2];
    __shared__ float v[64];
    __shared__ int   ix[64];
    __shared__ float zm[KP3];
    __shared__ float zr[256], h1[128], h2[64], lg[NCLS], red[2];
    int b = blockIdx.x, t = threadIdx.x;

    if (t < KP2) hl[t] = hsd[b * KP2 + t];
    __syncthreads();
    float sc = -INFINITY;
    if (t < KP2) {
        int i = b * KP2 + t;
        int s0 = off3[i], e0 = s0 + cnt3[i];
        float acc = 0.f;
        for (int j = s0; j < e0; ++j) acc += hl[csr[j].x - b*KP2];
        float di = dis3[i];
        sc = di * acc + hs[i] * (di * di) + bs3[0];
    }
    if (t < 64) { v[t] = sc; ix[t] = t; }
    __syncthreads();
    for (int size = 2; size <= 64; size <<= 1) {
        for (int stride = size >> 1; stride > 0; stride >>= 1) {
            if (t < 32) {
                int pos = 2 * t - (t & (stride - 1));
                int j2 = pos + stride;
                bool asc = (pos & size) == 0;
                float v0 = v[pos], v1 = v[j2];
                int i0 = ix[pos], i1 = ix[j2];
                bool jb = (v1 > v0) || (v1 == v0 && i1 < i0);
                bool sw = asc ? jb : !jb;
                if (sw) { v[pos] = v1; v[j2] = v0; ix[pos] = i1; ix[j2] = i0; }
            }
            __syncthreads();
        }
    }
    if (t < KP3) zm[t] = tanhf(v[t]);
    __syncthreads();
    // pool + readout directly into zr (no hA store — nothing consumes it)
    {
        float vmax = -INFINITY, vsum = 0.f;
        #pragma unroll
        for (int j = 0; j < KP3; ++j) {
            int src = b * KP2 + ix[j];
            float val = hout[(size_t)src * 128 + t] * zm[j];
            vmax = fmaxf(vmax, val); vsum += val;
        }
        zr[t] = z[b * 256 + t] + vmax;
        zr[128 + t] = z[b * 256 + 128 + t] + vsum / (float)KP3;
    }
    __syncthreads();
    // MLP head
    float acc = bl1[t];
    #pragma unroll 8
    for (int i = 0; i < 256; ++i) acc += zr[i] * Wl1[i * 128 + t];
    h1[t] = fmaxf(acc, 0.f);
    __syncthreads();
    if (t < 64) {
        float a2 = bl2[t];
        #pragma unroll 8
        for (int i = 0; i < 128; ++i) a2 += h1[i] * Wl2[i * 64 + t];
        h2[t] = fmaxf(a2, 0.f);
    }
    __syncthreads();
    if (t < NCLS) {
        float a3 = bl3[t];
        #pragma unroll 8
        for (int i = 0; i < 64; ++i) a3 += h2[i] * Wl3[i * NCLS + t];
        lg[t] = a3;
    }
    __syncthreads();
    if (t == 0) {
        float m = lg[0];
        for (int i = 1; i < NCLS; ++i) m = fmaxf(m, lg[i]);
        float s = 0.f;
        for (int i = 0; i < NCLS; ++i) s += expf(lg[i] - m);
        red[0] = m; red[1] = logf(s);
    }
    __syncthreads();
    if (t < NCLS) out[b * NCLS + t] = lg[t] - red[0] - red[1];
}

// ---------------- host ----------------
extern "C" void kernel_launch(void* const* d_in, const int* in_sizes, int n_in,
                              void* d_out, int out_size, void* d_ws, size_t ws_size,
                              hipStream_t stream) {
    const float* x   = (const float*)d_in[0];
    const int*   ei  = (const int*)d_in[1];
    const float* W1  = (const float*)d_in[2];  const float* b1  = (const float*)d_in[3];
    const float* W2  = (const float*)d_in[4];  const float* b2  = (const float*)d_in[5];
    const float* W3  = (const float*)d_in[6];  const float* b3  = (const float*)d_in[7];
    const float* Ws1 = (const float*)d_in[8];  const float* bs1 = (const float*)d_in[9];
    const float* Ws2 = (const float*)d_in[10]; const float* bs2 = (const float*)d_in[11];
    const float* Ws3 = (const float*)d_in[12]; const float* bs3 = (const float*)d_in[13];
    const float* Wl1 = (const float*)d_in[14]; const float* bl1 = (const float*)d_in[15];
    const float* Wl2 = (const float*)d_in[16]; const float* bl2 = (const float*)d_in[17];
    const float* Wl3 = (const float*)d_in[18]; const float* bl3 = (const float*)d_in[19];
    float* out = (float*)d_out;

    const int NMAX = NB * N0;  // 65536
    const int N1 = NB * KP1;   // 13120
    const int N2 = NB * KP2;   // 2624

    char* p = (char*)d_ws;
    float* z      = (float*)p; p += (size_t)NB * 256 * 4;
    float* hW     = (float*)p; p += (size_t)N1 * 128 * 4;
    float* hout   = (float*)p; p += (size_t)NMAX * 128 * 4;
    float* hA     = (float*)p; p += (size_t)N1 * 128 * 4;
    float* y      = (float*)p; p += (size_t)NMAX * FIN * 4;
    float* dis1   = (float*)p; p += (size_t)NMAX * 4;
    float* hs     = (float*)p; p += (size_t)NMAX * 4;
    float* hsd    = (float*)p; p += (size_t)NMAX * 4;
    int* newid1   = (int*)p;   p += (size_t)NMAX * 4;
    int* off1     = (int*)p;   p += (size_t)NMAX * 4;
    int* cnt1     = (int*)p;   p += (size_t)NMAX * 4;
    int* off2     = (int*)p;   p += (size_t)N1 * 4;
    int* cnt2     = (int*)p;   p += (size_t)N1 * 4;
    float* dis2   = (float*)p; p += (size_t)N1 * 4;
    int* off3     = (int*)p;   p += (size_t)N2 * 4;
    int* cnt3     = (int*)p;   p += (size_t)N2 * 4;
    float* dis3   = (float*)p; p += (size_t)N2 * 4;
    int2* csr2    = (int2*)p;  p += (size_t)NEDGE * 8;

    // ---------------- stage 1 ----------------
    build_csr1_k<<<NB, 1024, 0, stream>>>(ei, dis1, off1, cnt1, csr2);
    agg10_k<<<NB * 4, 256, 0, stream>>>(x, csr2, off1, cnt1, dis1, y);
    gemm_fin_fused_k<<<NMAX / 4, 256, 0, stream>>>(y, W1, b1, Ws1, dis1, hout, hs, hsd, NMAX);
    s1_topk_build2_k<<<NB, 1024, 0, stream>>>(hout, hs, hsd, ei, csr2, off1, cnt1, dis1,
                                              bs1, hA, z, newid1, off2, cnt2, dis2);

    // ---------------- stage 2 ----------------
    {
        dim3 g(ceil_div(N1, 64), 2);
        gemm128_tiled_k<<<g, 256, 0, stream>>>(hA, W2, hW, N1);
    }
    gcn_agg_fused2_k<<<N1 / 4, 256, 0, stream>>>(
        hW, csr2, off2, cnt2, dis2, b2, Ws2, hout, hs, hsd, N1, N1 / 32);
    s2_topk_build3_k<<<NB, 1024, 0, stream>>>(hout, hs, hsd, ei, csr2, off2, cnt2, dis2,
                                              bs2, newid1, hA, z, off3, cnt3, dis3);

    // ---------------- stage 3 ----------------
    {
        dim3 g(ceil_div(N2, 64), 2);
        gemm128_tiled_k<<<g, 256, 0, stream>>>(hA, W3, hW, N2);
    }
    gcn_agg_fused2_k<<<N2 / 4, 256, 0, stream>>>(
        hW, csr2, off3, cnt3, dis3, b3, Ws3, hout, hs, hsd, N2, N2 / 32);
    s3_topk_mlp_k<<<NB, 128, 0, stream>>>(hout, hs, hsd, csr2, off3, cnt3, dis3, bs3, z,
                                          Wl1, bl1, Wl2, bl2, Wl3, bl3, out);
}

// Round 15
// 271.240 us; speedup vs baseline: 1.1498x; 1.0016x over previous
//
#include <hip/hip_runtime.h>
#include <math.h>

#define NB 64          // graphs
#define N0 1024        // nodes per graph (stage 1)
#define NEDGE 1048576  // total edges
#define EPG 16384      // edges per graph — input edges are graph-grouped
#define FIN 10
#define NCLS 10
#define KP1 205
#define KP2 41
#define KP3 9

static inline int ceil_div(int a, int b) { return (a + b - 1) / b; }

// ---- block-wide inclusive scan via wave shfl + 16-wave combine (3 syncs) ----
__device__ __forceinline__ int block_scan_incl(int v, int* wtot, int lane, int wid) {
    __syncthreads();                    // protect wtot from previous use
    int x = v;
    #pragma unroll
    for (int s = 1; s < 64; s <<= 1) { int tv = __shfl_up(x, s); if (lane >= s) x += tv; }
    if (lane == 63) wtot[wid] = x;
    __syncthreads();
    if (wid == 0) {
        int w = (lane < 16) ? wtot[lane] : 0;
        #pragma unroll
        for (int s = 1; s < 16; s <<= 1) { int tv = __shfl_up(w, s); if (lane >= s) w += tv; }
        if (lane < 16) wtot[lane] = w;
    }
    __syncthreads();
    return x + ((wid > 0) ? wtot[wid - 1] : 0);
}

// order-preserving float->uint key
__device__ __forceinline__ unsigned fkey(float f) {
    unsigned b = __float_as_uint(f);
    return (f >= 0.f) ? (b | 0x80000000u) : ~b;
}

// ======== stage-1 CSR build: one block per graph, all-LDS =====
__global__ __launch_bounds__(1024) void build_csr1_k(const int* __restrict__ ei,
                                                     float* __restrict__ disg,
                                                     int* __restrict__ offg,
                                                     int* __restrict__ cntg,
                                                     int2* __restrict__ csr2) {
    __shared__ int cnt[N0];
    __shared__ int cur[N0];
    __shared__ float disl[N0];
    __shared__ int wtot[16];
    int b = blockIdx.x, t = threadIdx.x;
    int lane = t & 63, wid = t >> 6;
    cnt[t] = 0;
    __syncthreads();
    const int ebase = b * EPG;
    const int nbase = b * N0;
    #pragma unroll
    for (int u = 0; u < EPG / 1024; ++u) {
        int d = ei[NEDGE + ebase + u * 1024 + t] - nbase;
        atomicAdd(&cnt[d], 1);
    }
    __syncthreads();
    int v = cnt[t];
    int inc = block_scan_incl(v, wtot, lane, wid);
    int excl = inc - v;
    cur[t] = excl;
    float di = rsqrtf((float)v + 1.0f);
    disl[t] = di;
    offg[nbase + t] = ebase + excl;
    cntg[nbase + t] = v;
    disg[nbase + t] = di;
    __syncthreads();
    #pragma unroll
    for (int u = 0; u < EPG / 1024; ++u) {
        int j = ebase + u * 1024 + t;
        int s = ei[j], d = ei[NEDGE + j] - nbase;
        int pos = atomicAdd(&cur[d], 1);
        int2 o; o.x = s; o.y = __float_as_int(disl[s - nbase]);
        csr2[ebase + pos] = o;
    }
}

// ---------------- stage-1: aggregate RAW x (10-dim) pre-GEMM ----
__global__ __launch_bounds__(256) void agg10_k(const float* __restrict__ x,
                                               const int2* __restrict__ csr2,
                                               const int* __restrict__ off,
                                               const int* __restrict__ cnt,
                                               const float* __restrict__ dis,
                                               float* __restrict__ y) {
    __shared__ float xl[N0 * 11];
    int b = blockIdx.x >> 2, chunk = blockIdx.x & 3;
    const float* xg = x + (size_t)b * (N0 * FIN);
    for (int u = threadIdx.x; u < N0 * FIN; u += 256) {
        int r = u / FIN, c = u - r * FIN;
        xl[r * 11 + c] = xg[u];
    }
    __syncthreads();
    int li = chunk * 256 + threadIdx.x;
    int i  = b * N0 + li;
    int s0 = off[i], m = cnt[i];
    int base = b * N0;
    float acc[FIN];
    #pragma unroll
    for (int f = 0; f < FIN; ++f) acc[f] = 0.f;
    int j = 0;
    for (; j + 2 <= m; j += 2) {
        int2 e0 = csr2[s0 + j], e1 = csr2[s0 + j + 1];
        int sl0 = (e0.x - base) * 11, sl1 = (e1.x - base) * 11;
        float w0 = __int_as_float(e0.y), w1 = __int_as_float(e1.y);
        #pragma unroll
        for (int f = 0; f < FIN; ++f) acc[f] += xl[sl0 + f] * w0 + xl[sl1 + f] * w1;
    }
    if (j < m) {
        int2 e0 = csr2[s0 + j];
        int sl0 = (e0.x - base) * 11;
        float w0 = __int_as_float(e0.y);
        #pragma unroll
        for (int f = 0; f < FIN; ++f) acc[f] += xl[sl0 + f] * w0;
    }
    float di = dis[i], d2 = di * di;
    #pragma unroll
    for (int f = 0; f < FIN; ++f)
        y[(size_t)i * FIN + f] = di * acc[f] + d2 * xl[li * 11 + f];
}

// ---------------- fused: hout = relu(y@W + b); hs = hout@Wsc; hsd = hs*dis -------
__global__ void gemm_fin_fused_k(const float* __restrict__ y, const float* __restrict__ W,
                                 const float* __restrict__ bb, const float* __restrict__ Wsc,
                                 const float* __restrict__ dis,
                                 float* __restrict__ hout, float* __restrict__ hs,
                                 float* __restrict__ hsd, int n) {
    __shared__ float Ws[FIN * 128];
    __shared__ float Sc[128];
    for (int u = threadIdx.x; u < FIN * 128; u += 256) Ws[u] = W[u];
    if (threadIdx.x < 128) Sc[threadIdx.x] = Wsc[threadIdx.x];
    __syncthreads();
    int t = blockIdx.x * 256 + threadIdx.x;
    int i = t >> 6, lane = threadIdx.x & 63;
    if (i >= n) return;
    float a = (lane < FIN) ? y[(size_t)i * FIN + lane] : 0.f;
    const float2* W2 = (const float2*)Ws;
    float ax = bb[lane * 2], ay = bb[lane * 2 + 1];
    #pragma unroll
    for (int k = 0; k < FIN; ++k) {
        float ak = __shfl(a, k);
        float2 w = W2[k * 64 + lane];
        ax += ak * w.x; ay += ak * w.y;
    }
    ax = fmaxf(ax, 0.f); ay = fmaxf(ay, 0.f);
    float2 o; o.x = ax; o.y = ay;
    ((float2*)hout)[(size_t)i * 64 + lane] = o;
    float part = ax * Sc[lane * 2] + ay * Sc[lane * 2 + 1];
    #pragma unroll
    for (int sh = 32; sh >= 1; sh >>= 1) part += __shfl_xor(part, sh);
    if (lane == 0) { hs[i] = part; hsd[i] = part * dis[i]; }
}

// ====== STAGE-1: score + radix-select top-205 + pool + readout + BUILD stage-2 ====
__global__ __launch_bounds__(1024) void s1_topk_build2_k(
    const float* __restrict__ hout, const float* __restrict__ hs,
    const float* __restrict__ hsd, const int* __restrict__ ei,
    int2* __restrict__ csr,
    const int* __restrict__ off1, const int* __restrict__ cnt1,
    const float* __restrict__ dis1, const float* __restrict__ bs1,
    float* __restrict__ hA, float* __restrict__ z, int* __restrict__ newid1,
    int* __restrict__ off2, int* __restrict__ cnt2g, float* __restrict__ dis2g,
    int* __restrict__ dst2, int* __restrict__ etot2) {
    __shared__ float hl[1024];
    __shared__ unsigned u[1024];
    __shared__ int wtot[16];
    __shared__ unsigned tinfo[2];
    __shared__ int   n1l[1024];
    __shared__ int   seln[KP1];
    __shared__ float gatel[KP1];
    __shared__ float zm[1024];
    __shared__ float zs[1024];
    __shared__ int   c2[KP1];
    __shared__ int   cur2[KP1];
    __shared__ float d2l[KP1];
    int b = blockIdx.x, t = threadIdx.x;
    int lane = t & 63, wid = t >> 6;
    const int nbase = b * N0, ebase = b * EPG;

    hl[t] = hsd[nbase + t];
    __syncthreads();
    // score
    float sc;
    {
        int s0 = off1[nbase + t], e0 = s0 + cnt1[nbase + t];
        float acc = 0.f;
        int j = s0;
        for (; j + 4 <= e0; j += 4) {
            int a0 = csr[j].x, a1 = csr[j+1].x, a2 = csr[j+2].x, a3 = csr[j+3].x;
            acc += hl[a0 - nbase] + hl[a1 - nbase] + hl[a2 - nbase] + hl[a3 - nbase];
        }
        for (; j < e0; ++j) acc += hl[csr[j].x - nbase];
        float di = dis1[nbase + t];
        sc = di * acc + hs[nbase + t] * (di * di) + bs1[0];
    }
    unsigned kb = fkey(sc);
    u[t] = kb;
    __syncthreads();
    // single-wave radix select: threshold of K-th largest + count of ties to take
    if (wid == 0) {
        int remaining = KP1; unsigned prefix = 0;
        for (int bit = 31; bit >= 0; --bit) {
            int c = 0;
            #pragma unroll 4
            for (int i = lane; i < 1024; i += 64)
                c += ((u[i] >> bit) == ((prefix >> bit) | 1u));
            #pragma unroll
            for (int s = 32; s >= 1; s >>= 1) c += __shfl_xor(c, s);
            if (c >= remaining) prefix |= (1u << bit);
            else remaining -= c;
        }
        if (lane == 0) { tinfo[0] = prefix; tinfo[1] = (unsigned)remaining; }
    }
    __syncthreads();
    unsigned T = tinfo[0]; int extra = (int)tinfo[1];
    int gt = (kb > T), eq = (kb == T);
    int eqIncl = block_scan_incl(eq, wtot, lane, wid);
    int sel = gt || (eq && (eqIncl - eq) < extra);
    int selIncl = block_scan_incl(sel, wtot, lane, wid);
    int loc = selIncl - sel;
    if (sel) {
        n1l[t] = loc; seln[loc] = t; gatel[loc] = tanhf(sc);
        newid1[nbase + t] = b * KP1 + loc;
    } else {
        n1l[t] = -1; newid1[nbase + t] = -1;
    }
    __syncthreads();
    // pool gather + readout (G=8)
    {
        int g = t >> 7, f = t & 127;
        float vmax = -INFINITY, vsum = 0.f;
        for (int j = g; j < KP1; j += 8) {
            int src = nbase + seln[j];
            float val = hout[(size_t)src * 128 + f] * gatel[j];
            hA[((size_t)b * KP1 + j) * 128 + f] = val;
            vmax = fmaxf(vmax, val); vsum += val;
        }
        zm[t] = vmax; zs[t] = vsum;
        __syncthreads();
        if (t < 128) {
            float m = zm[t], s2 = zs[t];
            #pragma unroll
            for (int g2 = 1; g2 < 8; ++g2) { m = fmaxf(m, zm[g2 * 128 + t]); s2 += zs[g2 * 128 + t]; }
            z[b * 256 + t] = m;
            z[b * 256 + 128 + t] = s2 / (float)KP1;
        }
    }
    __syncthreads();
    // build stage-2 CSR + compact dst list
    if (t < KP1) c2[t] = 0;
    __syncthreads();
    #pragma unroll
    for (int uu = 0; uu < EPG / 1024; ++uu) {
        int j = ebase + uu * 1024 + t;
        int s = ei[j] - nbase, d = ei[NEDGE + j] - nbase;
        int ls = n1l[s], ld = n1l[d];
        if (ls >= 0 && ld >= 0) atomicAdd(&c2[ld], 1);
    }
    __syncthreads();
    int vv = (t < KP1) ? c2[t] : 0;
    int inc = block_scan_incl(vv, wtot, lane, wid);
    int excl = inc - vv;
    if (t < KP1) {
        cur2[t] = excl;
        float dd = rsqrtf((float)vv + 1.0f);
        d2l[t] = dd;
        off2[b * KP1 + t] = ebase + excl;
        cnt2g[b * KP1 + t] = vv;
        dis2g[b * KP1 + t] = dd;
    }
    if (t == 1023) etot2[b] = inc;
    __syncthreads();
    #pragma unroll
    for (int uu = 0; uu < EPG / 1024; ++uu) {
        int j = ebase + uu * 1024 + t;
        int s = ei[j] - nbase, d = ei[NEDGE + j] - nbase;
        int ls = n1l[s], ld = n1l[d];
        if (ls < 0 || ld < 0) continue;
        int pos = atomicAdd(&cur2[ld], 1);
        int2 o; o.x = b * KP1 + ls; o.y = __float_as_int(d2l[ls]);
        csr[ebase + pos] = o;
        dst2[ebase + pos] = ld;
    }
}

// ---------------- GEMM (K=128): 64x64 tile, 4x4 per thread, register-tiled -----
__global__ __launch_bounds__(256) void gemm128_tiled_k(const float* __restrict__ A,
                                                       const float* __restrict__ W,
                                                       float* __restrict__ C, int n) {
    __shared__ float As[64][33];
    __shared__ float Wt[32][64];
    int tx = threadIdx.x & 15, ty = threadIdx.x >> 4;
    int r0 = blockIdx.x * 64;
    int c0 = blockIdx.y * 64;
    float4 acc0 = {0,0,0,0}, acc1 = {0,0,0,0}, acc2 = {0,0,0,0}, acc3 = {0,0,0,0};
    int u = threadIdx.x;
    for (int k0 = 0; k0 < 128; k0 += 32) {
        __syncthreads();
        {
            int rr = u >> 3, cc = (u & 7) * 4;
            #pragma unroll
            for (int h = 0; h < 2; ++h) {
                int r = rr + h * 32;
                float4 v = {0,0,0,0};
                if (r0 + r < n) v = *(const float4*)&A[(size_t)(r0 + r) * 128 + k0 + cc];
                As[r][cc] = v.x; As[r][cc+1] = v.y; As[r][cc+2] = v.z; As[r][cc+3] = v.w;
            }
        }
        {
            int kk = u >> 4, c = (u & 15) * 4;
            #pragma unroll
            for (int h = 0; h < 2; ++h) {
                float4 v = *(const float4*)&W[(size_t)(k0 + kk + h * 16) * 128 + c0 + c];
                *(float4*)&Wt[kk + h * 16][c] = v;
            }
        }
        __syncthreads();
        #pragma unroll
        for (int kk = 0; kk < 32; ++kk) {
            float4 wv = *(const float4*)&Wt[kk][tx * 4];
            float a0 = As[ty * 4 + 0][kk];
            float a1 = As[ty * 4 + 1][kk];
            float a2 = As[ty * 4 + 2][kk];
            float a3 = As[ty * 4 + 3][kk];
            acc0.x += a0 * wv.x; acc0.y += a0 * wv.y; acc0.z += a0 * wv.z; acc0.w += a0 * wv.w;
            acc1.x += a1 * wv.x; acc1.y += a1 * wv.y; acc1.z += a1 * wv.z; acc1.w += a1 * wv.w;
            acc2.x += a2 * wv.x; acc2.y += a2 * wv.y; acc2.z += a2 * wv.z; acc2.w += a2 * wv.w;
            acc3.x += a3 * wv.x; acc3.y += a3 * wv.y; acc3.z += a3 * wv.z; acc3.w += a3 * wv.w;
        }
    }
    int r = r0 + ty * 4;
    if (r + 0 < n) *(float4*)&C[(size_t)(r + 0) * 128 + c0 + tx * 4] = acc0;
    if (r + 1 < n) *(float4*)&C[(size_t)(r + 1) * 128 + c0 + tx * 4] = acc1;
    if (r + 2 < n) *(float4*)&C[(size_t)(r + 2) * 128 + c0 + tx * 4] = acc2;
    if (r + 3 < n) *(float4*)&C[(size_t)(r + 3) * 128 + c0 + tx * 4] = acc3;
}

// ---------- fused GCN aggregation (stages 2/3): wave-per-node, XCD-swizzled --
__global__ void gcn_agg_fused2_k(const float* __restrict__ hW, const int2* __restrict__ csr2,
                                 const int* __restrict__ off, const int* __restrict__ cnt,
                                 const float* __restrict__ dis, const float* __restrict__ bias,
                                 const float* __restrict__ Wsc,
                                 float* __restrict__ hout, float* __restrict__ hs,
                                 float* __restrict__ hsd, int n, int cpx) {
    int wg = ((blockIdx.x & 7) * cpx) + (blockIdx.x >> 3);
    int t = wg * blockDim.x + threadIdx.x;
    int i = t >> 6;
    int lane = threadIdx.x & 63;
    if (i >= n) return;
    const float2* hW2 = (const float2*)hW;
    int s0 = off[i], e0 = s0 + cnt[i];
    float accx = 0.f, accy = 0.f;
    for (int j0 = s0; j0 < e0; j0 += 64) {
        int rem = e0 - j0;
        int m = rem < 64 ? rem : 64;
        int sv = 0; float wv = 0.f;
        if (lane < m) { int2 ec = csr2[j0 + lane]; sv = ec.x; wv = __int_as_float(ec.y); }
        int u = 0;
        for (; u + 4 <= m; u += 4) {
            int a0 = __shfl(sv, u + 0), a1 = __shfl(sv, u + 1);
            int a2 = __shfl(sv, u + 2), a3 = __shfl(sv, u + 3);
            float w0 = __shfl(wv, u + 0), w1 = __shfl(wv, u + 1);
            float w2 = __shfl(wv, u + 2), w3 = __shfl(wv, u + 3);
            float2 v0 = hW2[(size_t)a0 * 64 + lane];
            float2 v1 = hW2[(size_t)a1 * 64 + lane];
            float2 v2 = hW2[(size_t)a2 * 64 + lane];
            float2 v3 = hW2[(size_t)a3 * 64 + lane];
            accx += v0.x * w0 + v1.x * w1 + v2.x * w2 + v3.x * w3;
            accy += v0.y * w0 + v1.y * w1 + v2.y * w2 + v3.y * w3;
        }
        for (; u < m; ++u) {
            int s = __shfl(sv, u);
            float w = __shfl(wv, u);
            float2 v = hW2[(size_t)s * 64 + lane];
            accx += v.x * w; accy += v.y * w;
        }
    }
    float di = dis[i];
    float2 hv = hW2[(size_t)i * 64 + lane];
    float ox = fmaxf(di * accx + hv.x * (di * di) + bias[lane * 2], 0.f);
    float oy = fmaxf(di * accy + hv.y * (di * di) + bias[lane * 2 + 1], 0.f);
    float2 o; o.x = ox; o.y = oy;
    ((float2*)hout)[(size_t)i * 64 + lane] = o;
    float part = ox * Wsc[lane * 2] + oy * Wsc[lane * 2 + 1];
    #pragma unroll
    for (int sh = 32; sh >= 1; sh >>= 1) part += __shfl_xor(part, sh);
    if (lane == 0) { hs[i] = part; hsd[i] = part * di; }
}

// ====== STAGE-2: score + radix-select top-41 + pool + readout + BUILD stage-3 =====
__global__ __launch_bounds__(1024) void s2_topk_build3_k(
    const float* __restrict__ hout, const float* __restrict__ hs,
    const float* __restrict__ hsd,
    int2* __restrict__ csr, const int* __restrict__ dst2, const int* __restrict__ etot2,
    const int* __restrict__ off2, const int* __restrict__ cnt2,
    const float* __restrict__ dis2, const float* __restrict__ bs2,
    float* __restrict__ hA, float* __restrict__ z,
    int* __restrict__ off3, int* __restrict__ cnt3g, float* __restrict__ dis3g) {
    __shared__ float hl[256];
    __shared__ unsigned u2[256];
    __shared__ int wtot[16];
    __shared__ unsigned tinfo[2];
    __shared__ int   n2l[KP1];
    __shared__ int   seln[KP2];
    __shared__ float gatel[KP2];
    __shared__ float zm[1024];
    __shared__ float zs[1024];
    __shared__ int   c3[KP2];
    __shared__ int   cur3[KP2];
    __shared__ float d3l[KP2];
    int b = blockIdx.x, t = threadIdx.x;
    int lane = t & 63, wid = t >> 6;
    const int ebase = b * EPG;

    if (t < KP1) hl[t] = hsd[b * KP1 + t];
    __syncthreads();
    // score
    float sc = -INFINITY;
    if (t < KP1) {
        int i = b * KP1 + t;
        int s0 = off2[i], e0 = s0 + cnt2[i];
        float acc = 0.f;
        int j = s0;
        for (; j + 4 <= e0; j += 4) {
            int a0 = csr[j].x, a1 = csr[j+1].x, a2 = csr[j+2].x, a3 = csr[j+3].x;
            acc += hl[a0 - b*KP1] + hl[a1 - b*KP1] + hl[a2 - b*KP1] + hl[a3 - b*KP1];
        }
        for (; j < e0; ++j) acc += hl[csr[j].x - b*KP1];
        float di = dis2[i];
        sc = di * acc + hs[i] * (di * di) + bs2[0];
    }
    unsigned kb = fkey(sc);
    if (t < 256) u2[t] = kb;
    __syncthreads();
    if (wid == 0) {
        int remaining = KP2; unsigned prefix = 0;
        for (int bit = 31; bit >= 0; --bit) {
            int c = 0;
            #pragma unroll
            for (int i = lane; i < 256; i += 64)
                c += ((u2[i] >> bit) == ((prefix >> bit) | 1u));
            #pragma unroll
            for (int s = 32; s >= 1; s >>= 1) c += __shfl_xor(c, s);
            if (c >= remaining) prefix |= (1u << bit);
            else remaining -= c;
        }
        if (lane == 0) { tinfo[0] = prefix; tinfo[1] = (unsigned)remaining; }
    }
    __syncthreads();
    unsigned T = tinfo[0]; int extra = (int)tinfo[1];
    int valid = (t < KP1);
    int gt = valid && (kb > T), eq = valid && (kb == T);
    int eqIncl = block_scan_incl(eq, wtot, lane, wid);
    int sel = gt || (eq && (eqIncl - eq) < extra);
    int selIncl = block_scan_incl(sel, wtot, lane, wid);
    int loc = selIncl - sel;
    if (valid) {
        if (sel) { n2l[t] = loc; seln[loc] = t; gatel[loc] = tanhf(sc); }
        else     n2l[t] = -1;
    }
    __syncthreads();
    // pool gather + readout (G=8)
    {
        int g = t >> 7, f = t & 127;
        float vmax = -INFINITY, vsum = 0.f;
        for (int j = g; j < KP2; j += 8) {
            int src = b * KP1 + seln[j];
            float val = hout[(size_t)src * 128 + f] * gatel[j];
            hA[((size_t)b * KP2 + j) * 128 + f] = val;
            vmax = fmaxf(vmax, val); vsum += val;
        }
        zm[t] = vmax; zs[t] = vsum;
        __syncthreads();
        if (t < 128) {
            float m = zm[t], s2 = zs[t];
            #pragma unroll
            for (int g2 = 1; g2 < 8; ++g2) { m = fmaxf(m, zm[g2 * 128 + t]); s2 += zs[g2 * 128 + t]; }
            z[b * 256 + t] += m;
            z[b * 256 + 128 + t] += s2 / (float)KP2;
        }
    }
    __syncthreads();
    // ---- build stage-3 CSR from COMPACT stage-2 edge list ----
    int nE2 = etot2[b];
    int es[2], ed[2];
    #pragma unroll
    for (int r = 0; r < 2; ++r) {
        int i = r * 1024 + t;
        if (i < nE2) { es[r] = csr[ebase + i].x - b * KP1; ed[r] = dst2[ebase + i]; }
        else es[r] = -1;
    }
    __syncthreads();   // all compact reads done before csr overwrite
    if (t < KP2) c3[t] = 0;
    __syncthreads();
    int ms[2], md[2];
    #pragma unroll
    for (int r = 0; r < 2; ++r) {
        ms[r] = -1;
        if (es[r] >= 0) {
            int ls = n2l[es[r]], ld = n2l[ed[r]];
            if (ls >= 0 && ld >= 0) { ms[r] = ls; md[r] = ld; atomicAdd(&c3[ld], 1); }
        }
    }
    __syncthreads();
    int vv = (t < KP2) ? c3[t] : 0;
    int inc = block_scan_incl(vv, wtot, lane, wid);
    int excl = inc - vv;
    if (t < KP2) {
        cur3[t] = excl;
        float dd = rsqrtf((float)vv + 1.0f);
        d3l[t] = dd;
        off3[b * KP2 + t] = ebase + excl;
        cnt3g[b * KP2 + t] = vv;
        dis3g[b * KP2 + t] = dd;
    }
    __syncthreads();
    #pragma unroll
    for (int r = 0; r < 2; ++r) {
        if (ms[r] < 0) continue;
        int pos = atomicAdd(&cur3[md[r]], 1);
        int2 o; o.x = b * KP2 + ms[r]; o.y = __float_as_int(d3l[ms[r]]);
        csr[ebase + pos] = o;
    }
}

// ====== STAGE-3 top-k + pool + readout + MLP head (64x128) =======================
__global__ __launch_bounds__(128) void s3_topk_mlp_k(
    const float* __restrict__ hout, const float* __restrict__ hs,
    const float* __restrict__ hsd, const int2* __restrict__ csr,
    const int* __restrict__ off3, const int* __restrict__ cnt3,
    const float* __restrict__ dis3, const float* __restrict__ bs3,
    const float* __restrict__ z,
    const float* __restrict__ Wl1, const float* __restrict__ bl1,
    const float* __restrict__ Wl2, const float* __restrict__ bl2,
    const float* __restrict__ Wl3, const float* __restrict__ bl3,
    float* __restrict__ out) {
    __shared__ float hl[KP2];
    __shared__ float v[64];
    __shared__ int   ix[64];
    __shared__ float zm[KP3];
    __shared__ float zr[256], h1[128], h2[64], lg[NCLS], red[2];
    int b = blockIdx.x, t = threadIdx.x;

    if (t < KP2) hl[t] = hsd[b * KP2 + t];
    __syncthreads();
    float sc = -INFINITY;
    if (t < KP2) {
        int i = b * KP2 + t;
        int s0 = off3[i], e0 = s0 + cnt3[i];
        float acc = 0.f;
        for (int j = s0; j < e0; ++j) acc += hl[csr[j].x - b*KP2];
        float di = dis3[i];
        sc = di * acc + hs[i] * (di * di) + bs3[0];
    }
    if (t < 64) { v[t] = sc; ix[t] = t; }
    __syncthreads();
    for (int size = 2; size <= 64; size <<= 1) {
        for (int stride = size >> 1; stride > 0; stride >>= 1) {
            if (t < 32) {
                int pos = 2 * t - (t & (stride - 1));
                int j2 = pos + stride;
                bool asc = (pos & size) == 0;
                float v0 = v[pos], v1 = v[j2];
                int i0 = ix[pos], i1 = ix[j2];
                bool jb = (v1 > v0) || (v1 == v0 && i1 < i0);
                bool sw = asc ? jb : !jb;
                if (sw) { v[pos] = v1; v[j2] = v0; ix[pos] = i1; ix[j2] = i0; }
            }
            __syncthreads();
        }
    }
    if (t < KP3) zm[t] = tanhf(v[t]);
    __syncthreads();
    {
        float vmax = -INFINITY, vsum = 0.f;
        #pragma unroll
        for (int j = 0; j < KP3; ++j) {
            int src = b * KP2 + ix[j];
            float val = hout[(size_t)src * 128 + t] * zm[j];
            vmax = fmaxf(vmax, val); vsum += val;
        }
        zr[t] = z[b * 256 + t] + vmax;
        zr[128 + t] = z[b * 256 + 128 + t] + vsum / (float)KP3;
    }
    __syncthreads();
    float acc = bl1[t];
    #pragma unroll 8
    for (int i = 0; i < 256; ++i) acc += zr[i] * Wl1[i * 128 + t];
    h1[t] = fmaxf(acc, 0.f);
    __syncthreads();
    if (t < 64) {
        float a2 = bl2[t];
        #pragma unroll 8
        for (int i = 0; i < 128; ++i) a2 += h1[i] * Wl2[i * 64 + t];
        h2[t] = fmaxf(a2, 0.f);
    }
    __syncthreads();
    if (t < NCLS) {
        float a3 = bl3[t];
        #pragma unroll 8
        for (int i = 0; i < 64; ++i) a3 += h2[i] * Wl3[i * NCLS + t];
        lg[t] = a3;
    }
    __syncthreads();
    if (t == 0) {
        float m = lg[0];
        for (int i = 1; i < NCLS; ++i) m = fmaxf(m, lg[i]);
        float s = 0.f;
        for (int i = 0; i < NCLS; ++i) s += expf(lg[i] - m);
        red[0] = m; red[1] = logf(s);
    }
    __syncthreads();
    if (t < NCLS) out[b * NCLS + t] = lg[t] - red[0] - red[1];
}

// ---------------- host ----------------
extern "C" void kernel_launch(void* const* d_in, const int* in_sizes, int n_in,
                              void* d_out, int out_size, void* d_ws, size_t ws_size,
                              hipStream_t stream) {
    const float* x   = (const float*)d_in[0];
    const int*   ei  = (const int*)d_in[1];
    const float* W1  = (const float*)d_in[2];  const float* b1  = (const float*)d_in[3];
    const float* W2  = (const float*)d_in[4];  const float* b2  = (const float*)d_in[5];
    const float* W3  = (const float*)d_in[6];  const float* b3  = (const float*)d_in[7];
    const float* Ws1 = (const float*)d_in[8];  const float* bs1 = (const float*)d_in[9];
    const float* Ws2 = (const float*)d_in[10]; const float* bs2 = (const float*)d_in[11];
    const float* Ws3 = (const float*)d_in[12]; const float* bs3 = (const float*)d_in[13];
    const float* Wl1 = (const float*)d_in[14]; const float* bl1 = (const float*)d_in[15];
    const float* Wl2 = (const float*)d_in[16]; const float* bl2 = (const float*)d_in[17];
    const float* Wl3 = (const float*)d_in[18]; const float* bl3 = (const float*)d_in[19];
    float* out = (float*)d_out;

    const int NMAX = NB * N0;  // 65536
    const int N1 = NB * KP1;   // 13120
    const int N2 = NB * KP2;   // 2624

    char* p = (char*)d_ws;
    float* z      = (float*)p; p += (size_t)NB * 256 * 4;
    float* hW     = (float*)p; p += (size_t)N1 * 128 * 4;
    float* hout   = (float*)p; p += (size_t)NMAX * 128 * 4;
    float* hA     = (float*)p; p += (size_t)N1 * 128 * 4;
    float* y      = (float*)p; p += (size_t)NMAX * FIN * 4;
    float* dis1   = (float*)p; p += (size_t)NMAX * 4;
    float* hs     = (float*)p; p += (size_t)NMAX * 4;
    float* hsd    = (float*)p; p += (size_t)NMAX * 4;
    int* newid1   = (int*)p;   p += (size_t)NMAX * 4;
    int* off1     = (int*)p;   p += (size_t)NMAX * 4;
    int* cnt1     = (int*)p;   p += (size_t)NMAX * 4;
    int* off2     = (int*)p;   p += (size_t)N1 * 4;
    int* cnt2     = (int*)p;   p += (size_t)N1 * 4;
    float* dis2   = (float*)p; p += (size_t)N1 * 4;
    int* off3     = (int*)p;   p += (size_t)N2 * 4;
    int* cnt3     = (int*)p;   p += (size_t)N2 * 4;
    float* dis3   = (float*)p; p += (size_t)N2 * 4;
    int* dst2     = (int*)p;   p += (size_t)NEDGE * 4;
    int* etot2    = (int*)p;   p += (size_t)NB * 4;
    int2* csr2    = (int2*)p;  p += (size_t)NEDGE * 8;

    // ---------------- stage 1 ----------------
    build_csr1_k<<<NB, 1024, 0, stream>>>(ei, dis1, off1, cnt1, csr2);
    agg10_k<<<NB * 4, 256, 0, stream>>>(x, csr2, off1, cnt1, dis1, y);
    gemm_fin_fused_k<<<NMAX / 4, 256, 0, stream>>>(y, W1, b1, Ws1, dis1, hout, hs, hsd, NMAX);
    s1_topk_build2_k<<<NB, 1024, 0, stream>>>(hout, hs, hsd, ei, csr2, off1, cnt1, dis1,
                                              bs1, hA, z, newid1, off2, cnt2, dis2,
                                              dst2, etot2);

    // ---------------- stage 2 ----------------
    {
        dim3 g(ceil_div(N1, 64), 2);
        gemm128_tiled_k<<<g, 256, 0, stream>>>(hA, W2, hW, N1);
    }
    gcn_agg_fused2_k<<<N1 / 4, 256, 0, stream>>>(
        hW, csr2, off2, cnt2, dis2, b2, Ws2, hout, hs, hsd, N1, N1 / 32);
    s2_topk_build3_k<<<NB, 1024, 0, stream>>>(hout, hs, hsd, csr2, dst2, etot2,
                                              off2, cnt2, dis2, bs2, hA, z,
                                              off3, cnt3, dis3);

    // ---------------- stage 3 ----------------
    {
        dim3 g(ceil_div(N2, 64), 2);
        gemm128_tiled_k<<<g, 256, 0, stream>>>(hA, W3, hW, N2);
    }
    gcn_agg_fused2_k<<<N2 / 4, 256, 0, stream>>>(
        hW, csr2, off3, cnt3, dis3, b3, Ws3, hout, hs, hsd, N2, N2 / 32);
    s3_topk_mlp_k<<<NB, 128, 0, stream>>>(hout, hs, hsd, csr2, off3, cnt3, dis3, bs3, z,
                                          Wl1, bl1, Wl2, bl2, Wl3, bl3, out);
}

// Round 16
// 252.762 us; speedup vs baseline: 1.2339x; 1.0731x over previous
//
#include <hip/hip_runtime.h>
#include <math.h>

#define NB 64          // graphs
#define N0 1024        // nodes per graph (stage 1)
#define NEDGE 1048576  // total edges
#define EPG 16384      // edges per graph — input edges are graph-grouped
#define FIN 10
#define NCLS 10
#define KP1 205
#define KP2 41
#define KP3 9

static inline int ceil_div(int a, int b) { return (a + b - 1) / b; }

// ---- block-wide inclusive scan via wave shfl + 16-wave combine (3 syncs) ----
__device__ __forceinline__ int block_scan_incl(int v, int* wtot, int lane, int wid) {
    __syncthreads();
    int x = v;
    #pragma unroll
    for (int s = 1; s < 64; s <<= 1) { int tv = __shfl_up(x, s); if (lane >= s) x += tv; }
    if (lane == 63) wtot[wid] = x;
    __syncthreads();
    if (wid == 0) {
        int w = (lane < 16) ? wtot[lane] : 0;
        #pragma unroll
        for (int s = 1; s < 16; s <<= 1) { int tv = __shfl_up(w, s); if (lane >= s) w += tv; }
        if (lane < 16) wtot[lane] = w;
    }
    __syncthreads();
    return x + ((wid > 0) ? wtot[wid - 1] : 0);
}

// order-preserving float->uint key
__device__ __forceinline__ unsigned fkey(float f) {
    unsigned b = __float_as_uint(f);
    return (f >= 0.f) ? (b | 0x80000000u) : ~b;
}

// ---- parallel histogram top-K select: finds threshold key T and #ties to take ----
// 4 rounds of 8 bits; all threads build a 256-bin histogram, bucket walk by scan.
__device__ __forceinline__ void hist_select_topk(const unsigned* keys, int nkeys, int K,
                                                 int* hist, int* wtot, unsigned* tinfo,
                                                 int t, int lane, int wid,
                                                 unsigned& T, int& extra) {
    unsigned prefix = 0; int remaining = K;
    #pragma unroll
    for (int r = 0; r < 4; ++r) {
        int shift = 24 - 8 * r;
        if (t < 256) hist[t] = 0;
        __syncthreads();
        unsigned himask = (r == 0) ? 0u : (0xFFFFFFFFu << (shift + 8));
        for (int i = t; i < nkeys; i += 1024) {
            unsigned k = keys[i];
            if ((k & himask) == (prefix & himask))
                atomicAdd(&hist[(k >> shift) & 255], 1);
        }
        __syncthreads();
        int rv = (t < 256) ? hist[255 - t] : 0;
        int inc = block_scan_incl(rv, wtot, lane, wid);   // inc = count of keys in buckets >= (255-t)
        if (t < 256) {
            int cntAbove = inc - rv;
            if (cntAbove < remaining && inc >= remaining) {
                tinfo[2] = (unsigned)(255 - t); tinfo[3] = (unsigned)cntAbove;
            }
        }
        __syncthreads();
        prefix |= (tinfo[2] << shift);
        remaining -= (int)tinfo[3];
        __syncthreads();
    }
    T = prefix; extra = remaining;
}

// ======== stage-1 CSR build: one block per graph, edges register-cached =====
__global__ __launch_bounds__(1024) void build_csr1_k(const int* __restrict__ ei,
                                                     float* __restrict__ disg,
                                                     int* __restrict__ offg,
                                                     int* __restrict__ cntg,
                                                     int2* __restrict__ csr2) {
    __shared__ int cnt[N0];
    __shared__ int cur[N0];
    __shared__ float disl[N0];
    __shared__ int wtot[16];
    int b = blockIdx.x, t = threadIdx.x;
    int lane = t & 63, wid = t >> 6;
    cnt[t] = 0;
    __syncthreads();
    const int ebase = b * EPG;
    const int nbase = b * N0;
    int sreg[EPG / 1024], dreg[EPG / 1024];
    #pragma unroll
    for (int u = 0; u < EPG / 1024; ++u) {
        int j = ebase + u * 1024 + t;
        sreg[u] = ei[j] - nbase;
        dreg[u] = ei[NEDGE + j] - nbase;
        atomicAdd(&cnt[dreg[u]], 1);
    }
    __syncthreads();
    int v = cnt[t];
    int inc = block_scan_incl(v, wtot, lane, wid);
    int excl = inc - v;
    cur[t] = excl;
    float di = rsqrtf((float)v + 1.0f);
    disl[t] = di;
    offg[nbase + t] = ebase + excl;
    cntg[nbase + t] = v;
    disg[nbase + t] = di;
    __syncthreads();
    #pragma unroll
    for (int u = 0; u < EPG / 1024; ++u) {
        int pos = atomicAdd(&cur[dreg[u]], 1);
        int2 o; o.x = nbase + sreg[u]; o.y = __float_as_int(disl[sreg[u]]);
        csr2[ebase + pos] = o;
    }
}

// ---------------- stage-1: aggregate RAW x (10-dim) pre-GEMM ----
__global__ __launch_bounds__(256) void agg10_k(const float* __restrict__ x,
                                               const int2* __restrict__ csr2,
                                               const int* __restrict__ off,
                                               const int* __restrict__ cnt,
                                               const float* __restrict__ dis,
                                               float* __restrict__ y) {
    __shared__ float xl[N0 * 11];
    int b = blockIdx.x >> 2, chunk = blockIdx.x & 3;
    const float* xg = x + (size_t)b * (N0 * FIN);
    for (int u = threadIdx.x; u < N0 * FIN; u += 256) {
        int r = u / FIN, c = u - r * FIN;
        xl[r * 11 + c] = xg[u];
    }
    __syncthreads();
    int li = chunk * 256 + threadIdx.x;
    int i  = b * N0 + li;
    int s0 = off[i], m = cnt[i];
    int base = b * N0;
    float acc[FIN];
    #pragma unroll
    for (int f = 0; f < FIN; ++f) acc[f] = 0.f;
    int j = 0;
    for (; j + 2 <= m; j += 2) {
        int2 e0 = csr2[s0 + j], e1 = csr2[s0 + j + 1];
        int sl0 = (e0.x - base) * 11, sl1 = (e1.x - base) * 11;
        float w0 = __int_as_float(e0.y), w1 = __int_as_float(e1.y);
        #pragma unroll
        for (int f = 0; f < FIN; ++f) acc[f] += xl[sl0 + f] * w0 + xl[sl1 + f] * w1;
    }
    if (j < m) {
        int2 e0 = csr2[s0 + j];
        int sl0 = (e0.x - base) * 11;
        float w0 = __int_as_float(e0.y);
        #pragma unroll
        for (int f = 0; f < FIN; ++f) acc[f] += xl[sl0 + f] * w0;
    }
    float di = dis[i], d2 = di * di;
    #pragma unroll
    for (int f = 0; f < FIN; ++f)
        y[(size_t)i * FIN + f] = di * acc[f] + d2 * xl[li * 11 + f];
}

// ---------------- fused: hout = relu(y@W + b); hs = hout@Wsc; hsd = hs*dis -------
__global__ void gemm_fin_fused_k(const float* __restrict__ y, const float* __restrict__ W,
                                 const float* __restrict__ bb, const float* __restrict__ Wsc,
                                 const float* __restrict__ dis,
                                 float* __restrict__ hout, float* __restrict__ hs,
                                 float* __restrict__ hsd, int n) {
    __shared__ float Ws[FIN * 128];
    __shared__ float Sc[128];
    for (int u = threadIdx.x; u < FIN * 128; u += 256) Ws[u] = W[u];
    if (threadIdx.x < 128) Sc[threadIdx.x] = Wsc[threadIdx.x];
    __syncthreads();
    int t = blockIdx.x * 256 + threadIdx.x;
    int i = t >> 6, lane = threadIdx.x & 63;
    if (i >= n) return;
    float a = (lane < FIN) ? y[(size_t)i * FIN + lane] : 0.f;
    const float2* W2 = (const float2*)Ws;
    float ax = bb[lane * 2], ay = bb[lane * 2 + 1];
    #pragma unroll
    for (int k = 0; k < FIN; ++k) {
        float ak = __shfl(a, k);
        float2 w = W2[k * 64 + lane];
        ax += ak * w.x; ay += ak * w.y;
    }
    ax = fmaxf(ax, 0.f); ay = fmaxf(ay, 0.f);
    float2 o; o.x = ax; o.y = ay;
    ((float2*)hout)[(size_t)i * 64 + lane] = o;
    float part = ax * Sc[lane * 2] + ay * Sc[lane * 2 + 1];
    #pragma unroll
    for (int sh = 32; sh >= 1; sh >>= 1) part += __shfl_xor(part, sh);
    if (lane == 0) { hs[i] = part; hsd[i] = part * dis[i]; }
}

// ====== STAGE-1: score + hist-select top-205 + pool + readout + BUILD stage-2 =====
__global__ __launch_bounds__(1024) void s1_topk_build2_k(
    const float* __restrict__ hout, const float* __restrict__ hs,
    const float* __restrict__ hsd, const int* __restrict__ ei,
    int2* __restrict__ csr,
    const int* __restrict__ off1, const int* __restrict__ cnt1,
    const float* __restrict__ dis1, const float* __restrict__ bs1,
    float* __restrict__ z, int* __restrict__ rows1, float* __restrict__ gate1,
    int* __restrict__ off2, int* __restrict__ cnt2g, float* __restrict__ dis2g,
    int* __restrict__ dst2, int* __restrict__ etot2) {
    __shared__ float hl[1024];
    __shared__ unsigned u[1024];
    __shared__ int hist[256];
    __shared__ int wtot[16];
    __shared__ unsigned tinfo[4];
    __shared__ int   n1l[1024];
    __shared__ int   seln[KP1];
    __shared__ float gatel[KP1];
    __shared__ float zm[1024];
    __shared__ float zs[1024];
    __shared__ int   c2[KP1];
    __shared__ int   cur2[KP1];
    __shared__ float d2l[KP1];
    int b = blockIdx.x, t = threadIdx.x;
    int lane = t & 63, wid = t >> 6;
    const int nbase = b * N0, ebase = b * EPG;

    hl[t] = hsd[nbase + t];
    __syncthreads();
    // score
    float sc;
    {
        int s0 = off1[nbase + t], e0 = s0 + cnt1[nbase + t];
        float acc = 0.f;
        int j = s0;
        for (; j + 4 <= e0; j += 4) {
            int a0 = csr[j].x, a1 = csr[j+1].x, a2 = csr[j+2].x, a3 = csr[j+3].x;
            acc += hl[a0 - nbase] + hl[a1 - nbase] + hl[a2 - nbase] + hl[a3 - nbase];
        }
        for (; j < e0; ++j) acc += hl[csr[j].x - nbase];
        float di = dis1[nbase + t];
        sc = di * acc + hs[nbase + t] * (di * di) + bs1[0];
    }
    unsigned kb = fkey(sc);
    u[t] = kb;
    unsigned T; int extra;
    hist_select_topk(u, 1024, KP1, hist, wtot, tinfo, t, lane, wid, T, extra);
    int gt = (kb > T), eq = (kb == T);
    int eqIncl = block_scan_incl(eq, wtot, lane, wid);
    int sel = gt || (eq && (eqIncl - eq) < extra);
    int selIncl = block_scan_incl(sel, wtot, lane, wid);
    int loc = selIncl - sel;
    if (sel) {
        float g = tanhf(sc);
        n1l[t] = loc; seln[loc] = t; gatel[loc] = g;
        rows1[b * KP1 + loc] = nbase + t;
        gate1[b * KP1 + loc] = g;
    } else {
        n1l[t] = -1;
    }
    __syncthreads();
    // pool readout (G=8) — max/mean only, no hA store (stage-2 GEMM reads hout via rows1)
    {
        int g = t >> 7, f = t & 127;
        float vmax = -INFINITY, vsum = 0.f;
        for (int j = g; j < KP1; j += 8) {
            int src = nbase + seln[j];
            float val = hout[(size_t)src * 128 + f] * gatel[j];
            vmax = fmaxf(vmax, val); vsum += val;
        }
        zm[t] = vmax; zs[t] = vsum;
        __syncthreads();
        if (t < 128) {
            float m = zm[t], s2 = zs[t];
            #pragma unroll
            for (int g2 = 1; g2 < 8; ++g2) { m = fmaxf(m, zm[g2 * 128 + t]); s2 += zs[g2 * 128 + t]; }
            z[b * 256 + t] = m;
            z[b * 256 + 128 + t] = s2 / (float)KP1;
        }
    }
    __syncthreads();
    // build stage-2 CSR + compact dst list (edges mapped once, held in registers)
    if (t < KP1) c2[t] = 0;
    __syncthreads();
    int lsr[EPG / 1024], ldr[EPG / 1024];
    #pragma unroll
    for (int uu = 0; uu < EPG / 1024; ++uu) {
        int j = ebase + uu * 1024 + t;
        int s = ei[j] - nbase, d = ei[NEDGE + j] - nbase;
        int ls = n1l[s], ld = n1l[d];
        if (ls >= 0 && ld >= 0) { lsr[uu] = ls; ldr[uu] = ld; atomicAdd(&c2[ld], 1); }
        else lsr[uu] = -1;
    }
    __syncthreads();
    int vv = (t < KP1) ? c2[t] : 0;
    int inc = block_scan_incl(vv, wtot, lane, wid);
    int excl = inc - vv;
    if (t < KP1) {
        cur2[t] = excl;
        float dd = rsqrtf((float)vv + 1.0f);
        d2l[t] = dd;
        off2[b * KP1 + t] = ebase + excl;
        cnt2g[b * KP1 + t] = vv;
        dis2g[b * KP1 + t] = dd;
    }
    if (t == 1023) etot2[b] = inc;
    __syncthreads();
    #pragma unroll
    for (int uu = 0; uu < EPG / 1024; ++uu) {
        if (lsr[uu] < 0) continue;
        int pos = atomicAdd(&cur2[ldr[uu]], 1);
        int2 o; o.x = b * KP1 + lsr[uu]; o.y = __float_as_int(d2l[lsr[uu]]);
        csr[ebase + pos] = o;
        dst2[ebase + pos] = ldr[uu];
    }
}

// ------- GEMM (K=128): 64x64 tile, 4x4/thread; optional row-indirection + gate ----
__global__ __launch_bounds__(256) void gemm128_tiled_k(const float* __restrict__ A,
                                                       const float* __restrict__ W,
                                                       float* __restrict__ C, int n,
                                                       const int* __restrict__ rows,
                                                       const float* __restrict__ gate) {
    __shared__ float As[64][33];
    __shared__ float Wt[32][64];
    int tx = threadIdx.x & 15, ty = threadIdx.x >> 4;
    int r0 = blockIdx.x * 64;
    int c0 = blockIdx.y * 64;
    float4 acc0 = {0,0,0,0}, acc1 = {0,0,0,0}, acc2 = {0,0,0,0}, acc3 = {0,0,0,0};
    int u = threadIdx.x;
    for (int k0 = 0; k0 < 128; k0 += 32) {
        __syncthreads();
        {
            int rr = u >> 3, cc = (u & 7) * 4;
            #pragma unroll
            for (int h = 0; h < 2; ++h) {
                int r = rr + h * 32;
                float4 v = {0,0,0,0};
                if (r0 + r < n) {
                    int ar = rows ? rows[r0 + r] : (r0 + r);
                    v = *(const float4*)&A[(size_t)ar * 128 + k0 + cc];
                    if (gate) {
                        float g = gate[r0 + r];
                        v.x *= g; v.y *= g; v.z *= g; v.w *= g;
                    }
                }
                As[r][cc] = v.x; As[r][cc+1] = v.y; As[r][cc+2] = v.z; As[r][cc+3] = v.w;
            }
        }
        {
            int kk = u >> 4, c = (u & 15) * 4;
            #pragma unroll
            for (int h = 0; h < 2; ++h) {
                float4 v = *(const float4*)&W[(size_t)(k0 + kk + h * 16) * 128 + c0 + c];
                *(float4*)&Wt[kk + h * 16][c] = v;
            }
        }
        __syncthreads();
        #pragma unroll
        for (int kk = 0; kk < 32; ++kk) {
            float4 wv = *(const float4*)&Wt[kk][tx * 4];
            float a0 = As[ty * 4 + 0][kk];
            float a1 = As[ty * 4 + 1][kk];
            float a2 = As[ty * 4 + 2][kk];
            float a3 = As[ty * 4 + 3][kk];
            acc0.x += a0 * wv.x; acc0.y += a0 * wv.y; acc0.z += a0 * wv.z; acc0.w += a0 * wv.w;
            acc1.x += a1 * wv.x; acc1.y += a1 * wv.y; acc1.z += a1 * wv.z; acc1.w += a1 * wv.w;
            acc2.x += a2 * wv.x; acc2.y += a2 * wv.y; acc2.z += a2 * wv.z; acc2.w += a2 * wv.w;
            acc3.x += a3 * wv.x; acc3.y += a3 * wv.y; acc3.z += a3 * wv.z; acc3.w += a3 * wv.w;
        }
    }
    int r = r0 + ty * 4;
    if (r + 0 < n) *(float4*)&C[(size_t)(r + 0) * 128 + c0 + tx * 4] = acc0;
    if (r + 1 < n) *(float4*)&C[(size_t)(r + 1) * 128 + c0 + tx * 4] = acc1;
    if (r + 2 < n) *(float4*)&C[(size_t)(r + 2) * 128 + c0 + tx * 4] = acc2;
    if (r + 3 < n) *(float4*)&C[(size_t)(r + 3) * 128 + c0 + tx * 4] = acc3;
}

// ---------- fused GCN aggregation (stages 2/3): wave-per-node, XCD-swizzled --
__global__ void gcn_agg_fused2_k(const float* __restrict__ hW, const int2* __restrict__ csr2,
                                 const int* __restrict__ off, const int* __restrict__ cnt,
                                 const float* __restrict__ dis, const float* __restrict__ bias,
                                 const float* __restrict__ Wsc,
                                 float* __restrict__ hout, float* __restrict__ hs,
                                 float* __restrict__ hsd, int n, int cpx) {
    int wg = ((blockIdx.x & 7) * cpx) + (blockIdx.x >> 3);
    int t = wg * blockDim.x + threadIdx.x;
    int i = t >> 6;
    int lane = threadIdx.x & 63;
    if (i >= n) return;
    const float2* hW2 = (const float2*)hW;
    int s0 = off[i], e0 = s0 + cnt[i];
    float accx = 0.f, accy = 0.f;
    for (int j0 = s0; j0 < e0; j0 += 64) {
        int rem = e0 - j0;
        int m = rem < 64 ? rem : 64;
        int sv = 0; float wv = 0.f;
        if (lane < m) { int2 ec = csr2[j0 + lane]; sv = ec.x; wv = __int_as_float(ec.y); }
        int u = 0;
        for (; u + 4 <= m; u += 4) {
            int a0 = __shfl(sv, u + 0), a1 = __shfl(sv, u + 1);
            int a2 = __shfl(sv, u + 2), a3 = __shfl(sv, u + 3);
            float w0 = __shfl(wv, u + 0), w1 = __shfl(wv, u + 1);
            float w2 = __shfl(wv, u + 2), w3 = __shfl(wv, u + 3);
            float2 v0 = hW2[(size_t)a0 * 64 + lane];
            float2 v1 = hW2[(size_t)a1 * 64 + lane];
            float2 v2 = hW2[(size_t)a2 * 64 + lane];
            float2 v3 = hW2[(size_t)a3 * 64 + lane];
            accx += v0.x * w0 + v1.x * w1 + v2.x * w2 + v3.x * w3;
            accy += v0.y * w0 + v1.y * w1 + v2.y * w2 + v3.y * w3;
        }
        for (; u < m; ++u) {
            int s = __shfl(sv, u);
            float w = __shfl(wv, u);
            float2 v = hW2[(size_t)s * 64 + lane];
            accx += v.x * w; accy += v.y * w;
        }
    }
    float di = dis[i];
    float2 hv = hW2[(size_t)i * 64 + lane];
    float ox = fmaxf(di * accx + hv.x * (di * di) + bias[lane * 2], 0.f);
    float oy = fmaxf(di * accy + hv.y * (di * di) + bias[lane * 2 + 1], 0.f);
    float2 o; o.x = ox; o.y = oy;
    ((float2*)hout)[(size_t)i * 64 + lane] = o;
    float part = ox * Wsc[lane * 2] + oy * Wsc[lane * 2 + 1];
    #pragma unroll
    for (int sh = 32; sh >= 1; sh >>= 1) part += __shfl_xor(part, sh);
    if (lane == 0) { hs[i] = part; hsd[i] = part * di; }
}

// ====== STAGE-2: score + hist-select top-41 + pool + readout + BUILD stage-3 ======
__global__ __launch_bounds__(1024) void s2_topk_build3_k(
    const float* __restrict__ hout, const float* __restrict__ hs,
    const float* __restrict__ hsd,
    int2* __restrict__ csr, const int* __restrict__ dst2, const int* __restrict__ etot2,
    const int* __restrict__ off2, const int* __restrict__ cnt2,
    const float* __restrict__ dis2, const float* __restrict__ bs2,
    float* __restrict__ hA, float* __restrict__ z,
    int* __restrict__ off3, int* __restrict__ cnt3g, float* __restrict__ dis3g) {
    __shared__ float hl[256];
    __shared__ unsigned u2[256];
    __shared__ int hist[256];
    __shared__ int wtot[16];
    __shared__ unsigned tinfo[4];
    __shared__ int   n2l[KP1];
    __shared__ int   seln[KP2];
    __shared__ float gatel[KP2];
    __shared__ float zm[1024];
    __shared__ float zs[1024];
    __shared__ int   c3[KP2];
    __shared__ int   cur3[KP2];
    __shared__ float d3l[KP2];
    int b = blockIdx.x, t = threadIdx.x;
    int lane = t & 63, wid = t >> 6;
    const int ebase = b * EPG;

    if (t < KP1) hl[t] = hsd[b * KP1 + t];
    __syncthreads();
    // score
    float sc = -INFINITY;
    if (t < KP1) {
        int i = b * KP1 + t;
        int s0 = off2[i], e0 = s0 + cnt2[i];
        float acc = 0.f;
        int j = s0;
        for (; j + 4 <= e0; j += 4) {
            int a0 = csr[j].x, a1 = csr[j+1].x, a2 = csr[j+2].x, a3 = csr[j+3].x;
            acc += hl[a0 - b*KP1] + hl[a1 - b*KP1] + hl[a2 - b*KP1] + hl[a3 - b*KP1];
        }
        for (; j < e0; ++j) acc += hl[csr[j].x - b*KP1];
        float di = dis2[i];
        sc = di * acc + hs[i] * (di * di) + bs2[0];
    }
    unsigned kb = (t < KP1) ? fkey(sc) : 0u;
    if (t < 256) u2[t] = kb;
    unsigned T; int extra;
    hist_select_topk(u2, 256, KP2, hist, wtot, tinfo, t, lane, wid, T, extra);
    int valid = (t < KP1);
    int gt = valid && (kb > T), eq = valid && (kb == T);
    int eqIncl = block_scan_incl(eq, wtot, lane, wid);
    int sel = gt || (eq && (eqIncl - eq) < extra);
    int selIncl = block_scan_incl(sel, wtot, lane, wid);
    int loc = selIncl - sel;
    if (valid) {
        if (sel) { n2l[t] = loc; seln[loc] = t; gatel[loc] = tanhf(sc); }
        else     n2l[t] = -1;
    }
    __syncthreads();
    // pool gather + readout (G=8); hA kept for stage-3 GEMM (small)
    {
        int g = t >> 7, f = t & 127;
        float vmax = -INFINITY, vsum = 0.f;
        for (int j = g; j < KP2; j += 8) {
            int src = b * KP1 + seln[j];
            float val = hout[(size_t)src * 128 + f] * gatel[j];
            hA[((size_t)b * KP2 + j) * 128 + f] = val;
            vmax = fmaxf(vmax, val); vsum += val;
        }
        zm[t] = vmax; zs[t] = vsum;
        __syncthreads();
        if (t < 128) {
            float m = zm[t], s2 = zs[t];
            #pragma unroll
            for (int g2 = 1; g2 < 8; ++g2) { m = fmaxf(m, zm[g2 * 128 + t]); s2 += zs[g2 * 128 + t]; }
            z[b * 256 + t] += m;
            z[b * 256 + 128 + t] += s2 / (float)KP2;
        }
    }
    __syncthreads();
    // ---- build stage-3 CSR from COMPACT stage-2 edge list ----
    int nE2 = etot2[b];
    int es[2], ed[2];
    #pragma unroll
    for (int r = 0; r < 2; ++r) {
        int i = r * 1024 + t;
        if (i < nE2) { es[r] = csr[ebase + i].x - b * KP1; ed[r] = dst2[ebase + i]; }
        else es[r] = -1;
    }
    __syncthreads();
    if (t < KP2) c3[t] = 0;
    __syncthreads();
    int ms[2], md[2];
    #pragma unroll
    for (int r = 0; r < 2; ++r) {
        ms[r] = -1;
        if (es[r] >= 0) {
            int ls = n2l[es[r]], ld = n2l[ed[r]];
            if (ls >= 0 && ld >= 0) { ms[r] = ls; md[r] = ld; atomicAdd(&c3[ld], 1); }
        }
    }
    __syncthreads();
    int vv = (t < KP2) ? c3[t] : 0;
    int inc = block_scan_incl(vv, wtot, lane, wid);
    int excl = inc - vv;
    if (t < KP2) {
        cur3[t] = excl;
        float dd = rsqrtf((float)vv + 1.0f);
        d3l[t] = dd;
        off3[b * KP2 + t] = ebase + excl;
        cnt3g[b * KP2 + t] = vv;
        dis3g[b * KP2 + t] = dd;
    }
    __syncthreads();
    #pragma unroll
    for (int r = 0; r < 2; ++r) {
        if (ms[r] < 0) continue;
        int pos = atomicAdd(&cur3[md[r]], 1);
        int2 o; o.x = b * KP2 + ms[r]; o.y = __float_as_int(d3l[ms[r]]);
        csr[ebase + pos] = o;
    }
}

// ====== STAGE-3 top-k + pool + readout + MLP head (64x128) =======================
__global__ __launch_bounds__(128) void s3_topk_mlp_k(
    const float* __restrict__ hout, const float* __restrict__ hs,
    const float* __restrict__ hsd, const int2* __restrict__ csr,
    const int* __restrict__ off3, const int* __restrict__ cnt3,
    const float* __restrict__ dis3, const float* __restrict__ bs3,
    const float* __restrict__ z,
    const float* __restrict__ Wl1, const float* __restrict__ bl1,
    const float* __restrict__ Wl2, const float* __restrict__ bl2,
    const float* __restrict__ Wl3, const float* __restrict__ bl3,
    float* __restrict__ out) {
    __shared__ float hl[KP2];
    __shared__ float v[64];
    __shared__ int   ix[64];
    __shared__ float zm[KP3];
    __shared__ float zr[256], h1[128], h2[64], lg[NCLS], red[2];
    int b = blockIdx.x, t = threadIdx.x;

    if (t < KP2) hl[t] = hsd[b * KP2 + t];
    __syncthreads();
    float sc = -INFINITY;
    if (t < KP2) {
        int i = b * KP2 + t;
        int s0 = off3[i], e0 = s0 + cnt3[i];
        float acc = 0.f;
        for (int j = s0; j < e0; ++j) acc += hl[csr[j].x - b*KP2];
        float di = dis3[i];
        sc = di * acc + hs[i] * (di * di) + bs3[0];
    }
    if (t < 64) { v[t] = sc; ix[t] = t; }
    __syncthreads();
    for (int size = 2; size <= 64; size <<= 1) {
        for (int stride = size >> 1; stride > 0; stride >>= 1) {
            if (t < 32) {
                int pos = 2 * t - (t & (stride - 1));
                int j2 = pos + stride;
                bool asc = (pos & size) == 0;
                float v0 = v[pos], v1 = v[j2];
                int i0 = ix[pos], i1 = ix[j2];
                bool jb = (v1 > v0) || (v1 == v0 && i1 < i0);
                bool sw = asc ? jb : !jb;
                if (sw) { v[pos] = v1; v[j2] = v0; ix[pos] = i1; ix[j2] = i0; }
            }
            __syncthreads();
        }
    }
    if (t < KP3) zm[t] = tanhf(v[t]);
    __syncthreads();
    {
        float vmax = -INFINITY, vsum = 0.f;
        #pragma unroll
        for (int j = 0; j < KP3; ++j) {
            int src = b * KP2 + ix[j];
            float val = hout[(size_t)src * 128 + t] * zm[j];
            vmax = fmaxf(vmax, val); vsum += val;
        }
        zr[t] = z[b * 256 + t] + vmax;
        zr[128 + t] = z[b * 256 + 128 + t] + vsum / (float)KP3;
    }
    __syncthreads();
    float acc = bl1[t];
    #pragma unroll 8
    for (int i = 0; i < 256; ++i) acc += zr[i] * Wl1[i * 128 + t];
    h1[t] = fmaxf(acc, 0.f);
    __syncthreads();
    if (t < 64) {
        float a2 = bl2[t];
        #pragma unroll 8
        for (int i = 0; i < 128; ++i) a2 += h1[i] * Wl2[i * 64 + t];
        h2[t] = fmaxf(a2, 0.f);
    }
    __syncthreads();
    if (t < NCLS) {
        float a3 = bl3[t];
        #pragma unroll 8
        for (int i = 0; i < 64; ++i) a3 += h2[i] * Wl3[i * NCLS + t];
        lg[t] = a3;
    }
    __syncthreads();
    if (t == 0) {
        float m = lg[0];
        for (int i = 1; i < NCLS; ++i) m = fmaxf(m, lg[i]);
        float s = 0.f;
        for (int i = 0; i < NCLS; ++i) s += expf(lg[i] - m);
        red[0] = m; red[1] = logf(s);
    }
    __syncthreads();
    if (t < NCLS) out[b * NCLS + t] = lg[t] - red[0] - red[1];
}

// ---------------- host ----------------
extern "C" void kernel_launch(void* const* d_in, const int* in_sizes, int n_in,
                              void* d_out, int out_size, void* d_ws, size_t ws_size,
                              hipStream_t stream) {
    const float* x   = (const float*)d_in[0];
    const int*   ei  = (const int*)d_in[1];
    const float* W1  = (const float*)d_in[2];  const float* b1  = (const float*)d_in[3];
    const float* W2  = (const float*)d_in[4];  const float* b2  = (const float*)d_in[5];
    const float* W3  = (const float*)d_in[6];  const float* b3  = (const float*)d_in[7];
    const float* Ws1 = (const float*)d_in[8];  const float* bs1 = (const float*)d_in[9];
    const float* Ws2 = (const float*)d_in[10]; const float* bs2 = (const float*)d_in[11];
    const float* Ws3 = (const float*)d_in[12]; const float* bs3 = (const float*)d_in[13];
    const float* Wl1 = (const float*)d_in[14]; const float* bl1 = (const float*)d_in[15];
    const float* Wl2 = (const float*)d_in[16]; const float* bl2 = (const float*)d_in[17];
    const float* Wl3 = (const float*)d_in[18]; const float* bl3 = (const float*)d_in[19];
    float* out = (float*)d_out;

    const int NMAX = NB * N0;  // 65536
    const int N1 = NB * KP1;   // 13120
    const int N2 = NB * KP2;   // 2624

    char* p = (char*)d_ws;
    float* z      = (float*)p; p += (size_t)NB * 256 * 4;
    float* hW     = (float*)p; p += (size_t)N1 * 128 * 4;
    float* hout   = (float*)p; p += (size_t)NMAX * 128 * 4;
    float* hA     = (float*)p; p += (size_t)N1 * 128 * 4;
    float* y      = (float*)p; p += (size_t)NMAX * FIN * 4;
    float* dis1   = (float*)p; p += (size_t)NMAX * 4;
    float* hs     = (float*)p; p += (size_t)NMAX * 4;
    float* hsd    = (float*)p; p += (size_t)NMAX * 4;
    int* off1     = (int*)p;   p += (size_t)NMAX * 4;
    int* cnt1     = (int*)p;   p += (size_t)NMAX * 4;
    int* rows1    = (int*)p;   p += (size_t)N1 * 4;
    float* gate1  = (float*)p; p += (size_t)N1 * 4;
    int* off2     = (int*)p;   p += (size_t)N1 * 4;
    int* cnt2     = (int*)p;   p += (size_t)N1 * 4;
    float* dis2   = (float*)p; p += (size_t)N1 * 4;
    int* off3     = (int*)p;   p += (size_t)N2 * 4;
    int* cnt3     = (int*)p;   p += (size_t)N2 * 4;
    float* dis3   = (float*)p; p += (size_t)N2 * 4;
    int* dst2     = (int*)p;   p += (size_t)NEDGE * 4;
    int* etot2    = (int*)p;   p += (size_t)NB * 4;
    int2* csr2    = (int2*)p;  p += (size_t)NEDGE * 8;

    // ---------------- stage 1 ----------------
    build_csr1_k<<<NB, 1024, 0, stream>>>(ei, dis1, off1, cnt1, csr2);
    agg10_k<<<NB * 4, 256, 0, stream>>>(x, csr2, off1, cnt1, dis1, y);
    gemm_fin_fused_k<<<NMAX / 4, 256, 0, stream>>>(y, W1, b1, Ws1, dis1, hout, hs, hsd, NMAX);
    s1_topk_build2_k<<<NB, 1024, 0, stream>>>(hout, hs, hsd, ei, csr2, off1, cnt1, dis1,
                                              bs1, z, rows1, gate1, off2, cnt2, dis2,
                                              dst2, etot2);

    // ---------------- stage 2 (GEMM reads hout rows indirectly, gated) ----------------
    {
        dim3 g(ceil_div(N1, 64), 2);
        gemm128_tiled_k<<<g, 256, 0, stream>>>(hout, W2, hW, N1, rows1, gate1);
    }
    gcn_agg_fused2_k<<<N1 / 4, 256, 0, stream>>>(
        hW, csr2, off2, cnt2, dis2, b2, Ws2, hout, hs, hsd, N1, N1 / 32);
    s2_topk_build3_k<<<NB, 1024, 0, stream>>>(hout, hs, hsd, csr2, dst2, etot2,
                                              off2, cnt2, dis2, bs2, hA, z,
                                              off3, cnt3, dis3);

    // ---------------- stage 3 ----------------
    {
        dim3 g(ceil_div(N2, 64), 2);
        gemm128_tiled_k<<<g, 256, 0, stream>>>(hA, W3, hW, N2, nullptr, nullptr);
    }
    gcn_agg_fused2_k<<<N2 / 4, 256, 0, stream>>>(
        hW, csr2, off3, cnt3, dis3, b3, Ws3, hout, hs, hsd, N2, N2 / 32);
    s3_topk_mlp_k<<<NB, 128, 0, stream>>>(hout, hs, hsd, csr2, off3, cnt3, dis3, bs3, z,
                                          Wl1, bl1, Wl2, bl2, Wl3, bl3, out);
}